// Round 4
// baseline (1059.666 us; speedup 1.0000x reference)
//
#include <hip/hip_runtime.h>
#include <hip/hip_bf16.h>

#define D_MODEL 1024
#define D_STATE 16
#define D_INNER 2048
#define BSZ     4
#define SEQ     2048
#define NTOK    (BSZ*SEQ)     /* 8192 tokens */
#define NBIG    2176          /* 2048 (delta) + 16 (B) + 16 (C) + pad to 17*128 */
#define NCH     8             /* scan chunks per sequence */
#define TC      256           /* scan chunk length */

typedef __attribute__((ext_vector_type(8))) short short8;
typedef __attribute__((ext_vector_type(4))) float floatx4;

__device__ __forceinline__ ushort bf2us(float f)
{
    union { __hip_bfloat16 h; ushort u; } c;
    c.h = __float2bfloat16(f);
    return c.u;
}
__device__ __forceinline__ float us2f(ushort u)
{
    union { ushort u; __hip_bfloat16 h; } c;
    c.u = u;
    return __bfloat162float(c.h);
}

// ---------------------------------------------------------------- LayerNorm
__global__ __launch_bounds__(256) void ln_kernel(
    const float* __restrict__ x, const float* __restrict__ w,
    const float* __restrict__ bvec, __hip_bfloat16* __restrict__ out)
{
    int token = blockIdx.x;
    int tid = threadIdx.x;
    const float4 v = ((const float4*)(x + (size_t)token * D_MODEL))[tid];
    float s  = v.x + v.y + v.z + v.w;
    float sq = v.x*v.x + v.y*v.y + v.z*v.z + v.w*v.w;
#pragma unroll
    for (int o = 32; o; o >>= 1) { s += __shfl_down(s, o, 64); sq += __shfl_down(sq, o, 64); }
    __shared__ float red[8];
    int wid = tid >> 6;
    if ((tid & 63) == 0) { red[wid] = s; red[wid + 4] = sq; }
    __syncthreads();
    s  = red[0] + red[1] + red[2] + red[3];
    sq = red[4] + red[5] + red[6] + red[7];
    float mu  = s * (1.f / D_MODEL);
    float var = sq * (1.f / D_MODEL) - mu * mu;
    float rs  = rsqrtf(var + 1e-5f);
    float4 wv = ((const float4*)w)[tid];
    float4 bv = ((const float4*)bvec)[tid];
    union { ushort4 u; __hip_bfloat16 h[4]; } p;
    p.h[0] = __float2bfloat16((v.x - mu) * rs * wv.x + bv.x);
    p.h[1] = __float2bfloat16((v.y - mu) * rs * wv.y + bv.y);
    p.h[2] = __float2bfloat16((v.z - mu) * rs * wv.z + bv.z);
    p.h[3] = __float2bfloat16((v.w - mu) * rs * wv.w + bv.w);
    ((ushort4*)(out + (size_t)token * D_MODEL))[tid] = p.u;
}

// ------------------------------------------------- transpose + cast fp32->bf16
__global__ __launch_bounds__(256) void transpose_cast(
    const float* __restrict__ src, __hip_bfloat16* __restrict__ dst,
    int R, int C, int dstStride, int dstRowOff)
{
    __shared__ float tile[32][33];
    int tx = threadIdx.x, ty = threadIdx.y;  // 32 x 8
    int bx = blockIdx.x, by = blockIdx.y;
#pragma unroll
    for (int i = 0; i < 4; ++i) {
        int r = by * 32 + ty + i * 8;
        int c = bx * 32 + tx;
        if (r < R && c < C) tile[ty + i * 8][tx] = src[(size_t)r * C + c];
    }
    __syncthreads();
#pragma unroll
    for (int i = 0; i < 4; ++i) {
        int c = bx * 32 + ty + i * 8;
        int r = by * 32 + tx;
        if (c < C && r < R)
            dst[(size_t)(dstRowOff + c) * dstStride + r] = __float2bfloat16(tile[tx][ty + i * 8]);
    }
}

__global__ __launch_bounds__(256) void zero_fill(uint4* __restrict__ p, int n)
{
    int i = blockIdx.x * 256 + threadIdx.x;
    if (i < n) { uint4 z = {0, 0, 0, 0}; p[i] = z; }
}

// ---------------------------------------------------------------- bf16 GEMM
// C[M,N] = A[M,K] * BT[N,K]^T ; 128x128 tile, BK=64, 4 waves of 64x64.
// MODE 1: cols<2048 -> outB1 (x-path) bf16 ; cols>=2048 -> silu -> outB2 bf16
// MODE 2: cols<2048 -> outB1 bf16 = v + extra[col] (delta pre-softplus)
//         2048<=col<2080 -> outB2[row*32 + col-2048] bf16 (B|C); col>=2080 dropped
// MODE 3: outF[row*1024+col] = v + extra[row*1024+col]  (residual add)
template <int MODE>
__global__ __launch_bounds__(256) void gemm_bt(
    const __hip_bfloat16* __restrict__ A, const __hip_bfloat16* __restrict__ BT,
    int M, int N, int K,
    float* __restrict__ outF,
    __hip_bfloat16* __restrict__ outB1, __hip_bfloat16* __restrict__ outB2,
    const float* __restrict__ extra)
{
    __shared__ __align__(16) __hip_bfloat16 As[128 * 72];
    __shared__ __align__(16) __hip_bfloat16 Bs[128 * 72];
    int tid = threadIdx.x;
    int m0 = blockIdx.x * 128;
    int n0 = blockIdx.y * 128;
    int wid = tid >> 6, lane = tid & 63;
    int wm = (wid >> 1) * 64, wn = (wid & 1) * 64;
    int lr = lane & 15, lq = lane >> 4;

    floatx4 acc[4][4] = {};

    for (int k0 = 0; k0 < K; k0 += 64) {
        __syncthreads();
#pragma unroll
        for (int i = 0; i < 4; ++i) {
            int linear = (i * 256 + tid) * 8;
            int row = linear >> 6, col = linear & 63;
            *(int4*)(As + row * 72 + col) = *(const int4*)(A  + (size_t)(m0 + row) * K + k0 + col);
            *(int4*)(Bs + row * 72 + col) = *(const int4*)(BT + (size_t)(n0 + row) * K + k0 + col);
        }
        __syncthreads();
#pragma unroll
        for (int kk = 0; kk < 2; ++kk) {
            short8 af[4], bf[4];
#pragma unroll
            for (int mi = 0; mi < 4; ++mi)
                af[mi] = *(const short8*)(As + (wm + mi * 16 + lr) * 72 + kk * 32 + lq * 8);
#pragma unroll
            for (int ni = 0; ni < 4; ++ni)
                bf[ni] = *(const short8*)(Bs + (wn + ni * 16 + lr) * 72 + kk * 32 + lq * 8);
#pragma unroll
            for (int mi = 0; mi < 4; ++mi)
#pragma unroll
                for (int ni = 0; ni < 4; ++ni)
                    acc[mi][ni] = __builtin_amdgcn_mfma_f32_16x16x32_bf16(af[mi], bf[ni], acc[mi][ni], 0, 0, 0);
        }
    }

#pragma unroll
    for (int mi = 0; mi < 4; ++mi)
#pragma unroll
        for (int ni = 0; ni < 4; ++ni)
#pragma unroll
            for (int r = 0; r < 4; ++r) {
                int rg = m0 + wm + mi * 16 + lq * 4 + r;
                int cg = n0 + wn + ni * 16 + lr;
                float v = acc[mi][ni][r];
                if (MODE == 1) {
                    if (cg < D_INNER) {
                        outB1[(size_t)rg * D_INNER + cg] = __float2bfloat16(v);
                    } else {
                        float sv = v / (1.f + __expf(-v));
                        outB2[(size_t)rg * D_INNER + (cg - D_INNER)] = __float2bfloat16(sv);
                    }
                } else if (MODE == 2) {
                    if (cg < D_INNER) {
                        outB1[(size_t)rg * D_INNER + cg] = __float2bfloat16(v + extra[cg]);
                    } else if (cg < D_INNER + 32) {
                        outB2[(size_t)rg * 32 + (cg - D_INNER)] = __float2bfloat16(v);
                    }
                } else {
                    outF[(size_t)rg * D_MODEL + cg] = v + extra[(size_t)rg * D_MODEL + cg];
                }
            }
}

// ------------------------------------------- depthwise causal conv (K=4) + SiLU
// 32 chunks of 64 steps per (b,d): 262144 threads
__global__ __launch_bounds__(256) void conv_silu(
    const __hip_bfloat16* __restrict__ xin, const float* __restrict__ cw,
    const float* __restrict__ cb, __hip_bfloat16* __restrict__ xp)
{
    int gid = blockIdx.x * 256 + threadIdx.x;
    int d = gid & (D_INNER - 1);
    int rest = gid >> 11;
    int b = rest & 3;
    int ch = rest >> 2;          // 0..31
    int t0 = ch * 64;
    float w0 = cw[d * 4 + 0], w1 = cw[d * 4 + 1], w2 = cw[d * 4 + 2], w3 = cw[d * 4 + 3];
    float bias = cb[d];
    const __hip_bfloat16* base = xin + (size_t)b * SEQ * D_INNER + d;
    __hip_bfloat16* ob = xp + (size_t)b * SEQ * D_INNER + d;
    float xm3 = (t0 >= 3) ? __bfloat162float(base[(size_t)(t0 - 3) * D_INNER]) : 0.f;
    float xm2 = (t0 >= 2) ? __bfloat162float(base[(size_t)(t0 - 2) * D_INNER]) : 0.f;
    float xm1 = (t0 >= 1) ? __bfloat162float(base[(size_t)(t0 - 1) * D_INNER]) : 0.f;
#pragma unroll 4
    for (int t = t0; t < t0 + 64; ++t) {
        float xcur = __bfloat162float(base[(size_t)t * D_INNER]);
        float v = bias + w0 * xm3 + w1 * xm2 + w2 * xm1 + w3 * xcur;
        float sv = v / (1.f + __expf(-v));
        ob[(size_t)t * D_INNER] = __float2bfloat16(sv);
        xm3 = xm2; xm2 = xm1; xm1 = xcur;
    }
}

// ------------------------------------------------------------ chunked scan
// thread = (b, d, ch, s): s in 0..7 owns states n0=2s,2s+1; ch in 0..NCH-1.
__device__ __forceinline__ float softplus_f(float v)
{
    return (v > 20.f) ? v : __logf(1.f + __expf(v));
}

// pass 1: local scan from h=0, record final local state + decay product (bf16)
__global__ __launch_bounds__(256) void scan_p1(
    const __hip_bfloat16* __restrict__ deltaB, const __hip_bfloat16* __restrict__ xp,
    const __hip_bfloat16* __restrict__ BC, const float* __restrict__ A_log,
    ushort* __restrict__ hloc, ushort* __restrict__ prod)
{
    int gid = blockIdx.x * 256 + threadIdx.x;
    int s = gid & 7, ch = (gid >> 3) & 7, d = (gid >> 6) & (D_INNER - 1), b = gid >> 17;
    int n0 = s * 2;
    float2 Al = *(const float2*)(A_log + (size_t)d * D_STATE + n0);
    float A0 = -__expf(Al.x), A1 = -__expf(Al.y);
    float h0 = 0.f, h1 = 0.f, p0 = 1.f, p1 = 1.f;
    size_t mBase = (size_t)b * SEQ + ch * TC;
    for (int t = 0; t < TC; ++t) {
        size_t m = mBase + t;
        float dt = softplus_f(__bfloat162float(deltaB[m * D_INNER + d]));
        float xt = __bfloat162float(xp[m * D_INNER + d]);
        union { uint u; ushort2 us; } bv = { *(const uint*)((const ushort*)BC + m * 32 + n0) };
        float Bx = us2f(bv.us.x);
        float By = us2f(bv.us.y);
        float e0 = __expf(dt * A0), e1 = __expf(dt * A1);
        float dx = dt * xt;
        h0 = e0 * h0 + dx * Bx;
        h1 = e1 * h1 + dx * By;
        p0 *= e0; p1 *= e1;
    }
    size_t idx = (((size_t)(b * NCH + ch) * D_INNER + d) * D_STATE) + n0;
    ushort2 hs = { bf2us(h0), bf2us(h1) };
    ushort2 ps = { bf2us(p0), bf2us(p1) };
    *(ushort2*)(hloc + idx) = hs;
    *(ushort2*)(prod + idx) = ps;
}

// pass 1.5: sequential combine over chunks; hloc becomes h_in per chunk
__global__ __launch_bounds__(256) void scan_mid(
    ushort* __restrict__ hloc, const ushort* __restrict__ prod)
{
    int gid = blockIdx.x * 256 + threadIdx.x;   // 131072 = b(2) d(11) n(4)
    int n = gid & 15, d = (gid >> 4) & (D_INNER - 1), b = gid >> 15;
    float h = 0.f;
#pragma unroll
    for (int ch = 0; ch < NCH; ++ch) {
        size_t idx = (((size_t)(b * NCH + ch) * D_INNER + d) * D_STATE) + n;
        float old = us2f(hloc[idx]);
        float p   = us2f(prod[idx]);
        hloc[idx] = bf2us(h);
        h = old + p * h;
    }
}

// pass 2: rerun recurrence with correct h_in, produce yz = y * silu(z) in-place
__global__ __launch_bounds__(256) void scan_p2(
    const __hip_bfloat16* __restrict__ deltaB, const __hip_bfloat16* __restrict__ xp,
    const __hip_bfloat16* __restrict__ BC, const float* __restrict__ A_log,
    const float* __restrict__ D_param, const ushort* __restrict__ hin,
    __hip_bfloat16* __restrict__ zio)
{
    int gid = blockIdx.x * 256 + threadIdx.x;
    int s = gid & 7, ch = (gid >> 3) & 7, d = (gid >> 6) & (D_INNER - 1), b = gid >> 17;
    int n0 = s * 2;
    float2 Al = *(const float2*)(A_log + (size_t)d * D_STATE + n0);
    float A0 = -__expf(Al.x), A1 = -__expf(Al.y);
    float Dp = D_param[d];
    size_t idx = (((size_t)(b * NCH + ch) * D_INNER + d) * D_STATE) + n0;
    union { uint u; ushort2 us; } hv = { *(const uint*)(hin + idx) };
    float h0 = us2f(hv.us.x);
    float h1 = us2f(hv.us.y);
    size_t mBase = (size_t)b * SEQ + ch * TC;
    for (int t = 0; t < TC; ++t) {
        size_t m = mBase + t;
        float dt = softplus_f(__bfloat162float(deltaB[m * D_INNER + d]));
        float xt = __bfloat162float(xp[m * D_INNER + d]);
        union { uint u; ushort2 us; } bv = { *(const uint*)((const ushort*)BC + m * 32 + n0) };
        union { uint u; ushort2 us; } cv = { *(const uint*)((const ushort*)BC + m * 32 + 16 + n0) };
        float Bx = us2f(bv.us.x);
        float By = us2f(bv.us.y);
        float Cx = us2f(cv.us.x);
        float Cy = us2f(cv.us.y);
        float e0 = __expf(dt * A0), e1 = __expf(dt * A1);
        float dx = dt * xt;
        h0 = e0 * h0 + dx * Bx;
        h1 = e1 * h1 + dx * By;
        float part = h0 * Cx + h1 * Cy;
        part += __shfl_xor(part, 1, 64);
        part += __shfl_xor(part, 2, 64);
        part += __shfl_xor(part, 4, 64);
        if (s == 0) {
            float y = part + Dp * xt;
            float z = __bfloat162float(zio[m * D_INNER + d]);
            zio[m * D_INNER + d] = __float2bfloat16(y * z);
        }
    }
}

// ------------------------------------------------------------------ launch
extern "C" void kernel_launch(void* const* d_in, const int* in_sizes, int n_in,
                              void* d_out, int out_size, void* d_ws, size_t ws_size,
                              hipStream_t stream)
{
    const float* x       = (const float*)d_in[0];
    const float* norm_w  = (const float*)d_in[1];
    const float* norm_b  = (const float*)d_in[2];
    const float* W_in    = (const float*)d_in[3];
    const float* conv_w  = (const float*)d_in[4];
    const float* conv_b  = (const float*)d_in[5];
    const float* A_log   = (const float*)d_in[6];
    const float* W_b     = (const float*)d_in[7];
    const float* W_c     = (const float*)d_in[8];
    const float* W_delta = (const float*)d_in[9];
    const float* b_delta = (const float*)d_in[10];
    const float* D_param = (const float*)d_in[11];
    const float* W_out   = (const float*)d_in[12];
    float* out = (float*)d_out;

    // ---- workspace: 110.1 MB total (R2 lesson: 210 MB overflowed d_ws and
    //      corrupted the harness's pristine input copies). Heavy aliasing.
    char* ws = (char*)d_ws;
    char* R_xp   = ws;                              // 33,554,432
    char* R_xraw = R_xp   + (size_t)33554432;       // 33,554,432
    char* R_z    = R_xraw + (size_t)33554432;       // 33,554,432
    char* R_wT2  = R_z    + (size_t)33554432;       //  8,912,896
    char* R_BC   = R_wT2  + (size_t)8912896;        //    524,288   => 110,100,480 total

    // lifetimes:
    __hip_bfloat16* xnb    = (__hip_bfloat16*)R_xp;                    // ln .. gemm1
    __hip_bfloat16* wT1    = (__hip_bfloat16*)(R_xp + 16777216);       // trW_in .. gemm1
    __hip_bfloat16* xp     = (__hip_bfloat16*)R_xp;                    // conv .. scan_p2 (overwrites xnb+wT1)
    __hip_bfloat16* xraw   = (__hip_bfloat16*)R_xraw;                  // gemm1 .. conv
    __hip_bfloat16* deltaB = (__hip_bfloat16*)R_xraw;                  // gemm2 .. scan_p2 (over dead xraw)
    __hip_bfloat16* zio    = (__hip_bfloat16*)R_z;                     // zsilu then yz in-place
    __hip_bfloat16* wT2    = (__hip_bfloat16*)R_wT2;                   // tr .. gemm2 (2176x2048)
    ushort*         hloc   = (ushort*)R_wT2;                           // scan_p1.. (2 MB, over dead wT2)
    ushort*         prodb  = (ushort*)(R_wT2 + 2097152);               // scan_p1.. (2 MB)
    __hip_bfloat16* wT3    = (__hip_bfloat16*)(R_wT2 + 4194304);       // trW_out .. gemm3 (4.19 MB)
    __hip_bfloat16* BCb    = (__hip_bfloat16*)R_BC;                    // gemm2 .. scan

    // 1. LayerNorm -> bf16
    ln_kernel<<<NTOK, 256, 0, stream>>>(x, norm_w, norm_b, xnb);

    // 2. W_in^T -> wT1 (4096 rows, K-stride 1024)
    transpose_cast<<<dim3(128, 32), dim3(32, 8), 0, stream>>>(W_in, wT1, 1024, 4096, 1024, 0);

    // 3. xz = xn @ W_in -> xraw (x-path) + silu(z) -> zio
    gemm_bt<1><<<dim3(NTOK / 128, 4096 / 128), 256, 0, stream>>>(
        xnb, wT1, NTOK, 4096, 1024, nullptr, xraw, zio, nullptr);

    // 4. [W_delta | W_b | W_c | 0]^T -> wT2 (2176 rows, stride 2048)
    transpose_cast<<<dim3(64, 64), dim3(32, 8), 0, stream>>>(W_delta, wT2, 2048, 2048, 2048, 0);
    transpose_cast<<<dim3(1, 64),  dim3(32, 8), 0, stream>>>(W_b,     wT2, 2048, 16,   2048, 2048);
    transpose_cast<<<dim3(1, 64),  dim3(32, 8), 0, stream>>>(W_c,     wT2, 2048, 16,   2048, 2064);
    zero_fill<<<96, 256, 0, stream>>>((uint4*)(wT2 + (size_t)2080 * 2048), 24576);

    // 5. depthwise causal conv + silu: xraw -> xp (overwrites xnb/wT1 region)
    conv_silu<<<1024, 256, 0, stream>>>(xraw, conv_w, conv_b, xp);

    // 6. [delta|B|C] = xp @ wT2^T -> deltaB bf16 (over xraw) + BCb bf16
    gemm_bt<2><<<dim3(NTOK / 128, NBIG / 128), 256, 0, stream>>>(
        xp, wT2, NTOK, NBIG, 2048, nullptr, deltaB, BCb, b_delta);

    // 7. chunked scan (wT2 dead -> hloc/prod live there)
    scan_p1<<<2048, 256, 0, stream>>>(deltaB, xp, BCb, A_log, hloc, prodb);
    scan_mid<<<512, 256, 0, stream>>>(hloc, prodb);

    // 8. W_out^T -> wT3 (after gemm2: region overlapped old wT2 rows)
    transpose_cast<<<dim3(32, 64), dim3(32, 8), 0, stream>>>(W_out, wT3, 2048, 1024, 2048, 0);

    // 9. scan pass 2 -> yz in-place over zio
    scan_p2<<<2048, 256, 0, stream>>>(deltaB, xp, BCb, A_log, D_param, hloc, zio);

    // 10. out = yz @ W_out + residual
    gemm_bt<3><<<dim3(NTOK / 128, D_MODEL / 128), 256, 0, stream>>>(
        zio, wT3, NTOK, D_MODEL, 2048, out, nullptr, nullptr, x);

    (void)in_sizes; (void)n_in; (void)out_size; (void)ws_size;
}

// Round 5
// 734.268 us; speedup vs baseline: 1.4432x; 1.4432x over previous
//
#include <hip/hip_runtime.h>
#include <hip/hip_bf16.h>

#define D_MODEL 1024
#define D_STATE 16
#define D_INNER 2048
#define BSZ     4
#define SEQ     2048
#define NTOK    (BSZ*SEQ)     /* 8192 tokens */
#define NBIG    2176          /* 2048 (delta) + 16 (B) + 16 (C) + pad to 17*128 */
#define NCH     16            /* scan chunks per sequence */
#define TC      128           /* scan chunk length */

typedef __attribute__((ext_vector_type(8))) short short8;
typedef __attribute__((ext_vector_type(4))) float floatx4;

__device__ __forceinline__ ushort bf2us(float f)
{
    union { __hip_bfloat16 h; ushort u; } c;
    c.h = __float2bfloat16(f);
    return c.u;
}
__device__ __forceinline__ float us2f(ushort u)
{
    union { uint u; float f; } c;
    c.u = ((uint)u) << 16;
    return c.f;
}
__device__ __forceinline__ uint pk2(float a, float b)
{
    return (uint)bf2us(a) | ((uint)bf2us(b) << 16);
}
// unpack 8 bf16 (one uint4) -> 8 fp32; element order preserved
__device__ __forceinline__ void unpack8(uint4 r, float* f)
{
    f[0] = __uint_as_float(r.x << 16); f[1] = __uint_as_float(r.x & 0xffff0000u);
    f[2] = __uint_as_float(r.y << 16); f[3] = __uint_as_float(r.y & 0xffff0000u);
    f[4] = __uint_as_float(r.z << 16); f[5] = __uint_as_float(r.z & 0xffff0000u);
    f[6] = __uint_as_float(r.w << 16); f[7] = __uint_as_float(r.w & 0xffff0000u);
}
__device__ __forceinline__ float softplus_f(float v)
{
    return (v > 20.f) ? v : __logf(1.f + __expf(v));
}

// ---------------------------------------------------------------- LayerNorm
__global__ __launch_bounds__(256) void ln_kernel(
    const float* __restrict__ x, const float* __restrict__ w,
    const float* __restrict__ bvec, __hip_bfloat16* __restrict__ out)
{
    int token = blockIdx.x;
    int tid = threadIdx.x;
    const float4 v = ((const float4*)(x + (size_t)token * D_MODEL))[tid];
    float s  = v.x + v.y + v.z + v.w;
    float sq = v.x*v.x + v.y*v.y + v.z*v.z + v.w*v.w;
#pragma unroll
    for (int o = 32; o; o >>= 1) { s += __shfl_down(s, o, 64); sq += __shfl_down(sq, o, 64); }
    __shared__ float red[8];
    int wid = tid >> 6;
    if ((tid & 63) == 0) { red[wid] = s; red[wid + 4] = sq; }
    __syncthreads();
    s  = red[0] + red[1] + red[2] + red[3];
    sq = red[4] + red[5] + red[6] + red[7];
    float mu  = s * (1.f / D_MODEL);
    float var = sq * (1.f / D_MODEL) - mu * mu;
    float rs  = rsqrtf(var + 1e-5f);
    float4 wv = ((const float4*)w)[tid];
    float4 bv = ((const float4*)bvec)[tid];
    union { ushort4 u; __hip_bfloat16 h[4]; } p;
    p.h[0] = __float2bfloat16((v.x - mu) * rs * wv.x + bv.x);
    p.h[1] = __float2bfloat16((v.y - mu) * rs * wv.y + bv.y);
    p.h[2] = __float2bfloat16((v.z - mu) * rs * wv.z + bv.z);
    p.h[3] = __float2bfloat16((v.w - mu) * rs * wv.w + bv.w);
    ((ushort4*)(out + (size_t)token * D_MODEL))[tid] = p.u;
}

// ------------------------------------------------- transpose + cast fp32->bf16
__global__ __launch_bounds__(256) void transpose_cast(
    const float* __restrict__ src, __hip_bfloat16* __restrict__ dst,
    int R, int C, int dstStride, int dstRowOff)
{
    __shared__ float tile[32][33];
    int tx = threadIdx.x, ty = threadIdx.y;  // 32 x 8
    int bx = blockIdx.x, by = blockIdx.y;
#pragma unroll
    for (int i = 0; i < 4; ++i) {
        int r = by * 32 + ty + i * 8;
        int c = bx * 32 + tx;
        if (r < R && c < C) tile[ty + i * 8][tx] = src[(size_t)r * C + c];
    }
    __syncthreads();
#pragma unroll
    for (int i = 0; i < 4; ++i) {
        int c = bx * 32 + ty + i * 8;
        int r = by * 32 + tx;
        if (c < C && r < R)
            dst[(size_t)(dstRowOff + c) * dstStride + r] = __float2bfloat16(tile[tx][ty + i * 8]);
    }
}

__global__ __launch_bounds__(256) void zero_fill(uint4* __restrict__ p, int n)
{
    int i = blockIdx.x * 256 + threadIdx.x;
    if (i < n) { uint4 z = {0, 0, 0, 0}; p[i] = z; }
}

// ---------------------------------------------------------------- bf16 GEMM
// C[M,N] = A[M,K] * BT[N,K]^T ; 128x128 tile, BK=64, 4 waves of 64x64.
// MODE 1: cols<2048 -> outB1 (x-path) bf16 ; cols>=2048 -> silu -> outB2 bf16
// MODE 2: cols<2048 -> outB1 bf16 = softplus(v + extra[col])   (dt, final)
//         2048<=col<2080 -> outB2[row*32 + col-2048] bf16 (B|C); col>=2080 dropped
// MODE 3: outF[row*1024+col] = v + extra[row*1024+col]  (residual add)
template <int MODE>
__global__ __launch_bounds__(256) void gemm_bt(
    const __hip_bfloat16* __restrict__ A, const __hip_bfloat16* __restrict__ BT,
    int M, int N, int K,
    float* __restrict__ outF,
    __hip_bfloat16* __restrict__ outB1, __hip_bfloat16* __restrict__ outB2,
    const float* __restrict__ extra)
{
    __shared__ __align__(16) __hip_bfloat16 As[128 * 72];
    __shared__ __align__(16) __hip_bfloat16 Bs[128 * 72];
    int tid = threadIdx.x;
    int m0 = blockIdx.x * 128;
    int n0 = blockIdx.y * 128;
    int wid = tid >> 6, lane = tid & 63;
    int wm = (wid >> 1) * 64, wn = (wid & 1) * 64;
    int lr = lane & 15, lq = lane >> 4;

    floatx4 acc[4][4] = {};

    for (int k0 = 0; k0 < K; k0 += 64) {
        __syncthreads();
#pragma unroll
        for (int i = 0; i < 4; ++i) {
            int linear = (i * 256 + tid) * 8;
            int row = linear >> 6, col = linear & 63;
            *(int4*)(As + row * 72 + col) = *(const int4*)(A  + (size_t)(m0 + row) * K + k0 + col);
            *(int4*)(Bs + row * 72 + col) = *(const int4*)(BT + (size_t)(n0 + row) * K + k0 + col);
        }
        __syncthreads();
#pragma unroll
        for (int kk = 0; kk < 2; ++kk) {
            short8 af[4], bf[4];
#pragma unroll
            for (int mi = 0; mi < 4; ++mi)
                af[mi] = *(const short8*)(As + (wm + mi * 16 + lr) * 72 + kk * 32 + lq * 8);
#pragma unroll
            for (int ni = 0; ni < 4; ++ni)
                bf[ni] = *(const short8*)(Bs + (wn + ni * 16 + lr) * 72 + kk * 32 + lq * 8);
#pragma unroll
            for (int mi = 0; mi < 4; ++mi)
#pragma unroll
                for (int ni = 0; ni < 4; ++ni)
                    acc[mi][ni] = __builtin_amdgcn_mfma_f32_16x16x32_bf16(af[mi], bf[ni], acc[mi][ni], 0, 0, 0);
        }
    }

#pragma unroll
    for (int mi = 0; mi < 4; ++mi)
#pragma unroll
        for (int ni = 0; ni < 4; ++ni)
#pragma unroll
            for (int r = 0; r < 4; ++r) {
                int rg = m0 + wm + mi * 16 + lq * 4 + r;
                int cg = n0 + wn + ni * 16 + lr;
                float v = acc[mi][ni][r];
                if (MODE == 1) {
                    if (cg < D_INNER) {
                        outB1[(size_t)rg * D_INNER + cg] = __float2bfloat16(v);
                    } else {
                        float sv = v / (1.f + __expf(-v));
                        outB2[(size_t)rg * D_INNER + (cg - D_INNER)] = __float2bfloat16(sv);
                    }
                } else if (MODE == 2) {
                    if (cg < D_INNER) {
                        outB1[(size_t)rg * D_INNER + cg] = __float2bfloat16(softplus_f(v + extra[cg]));
                    } else if (cg < D_INNER + 32) {
                        outB2[(size_t)rg * 32 + (cg - D_INNER)] = __float2bfloat16(v);
                    }
                } else {
                    outF[(size_t)rg * D_MODEL + cg] = v + extra[(size_t)rg * D_MODEL + cg];
                }
            }
}

// ------------------------------------------- depthwise causal conv (K=4) + SiLU
__global__ __launch_bounds__(256) void conv_silu(
    const __hip_bfloat16* __restrict__ xin, const float* __restrict__ cw,
    const float* __restrict__ cb, __hip_bfloat16* __restrict__ xp)
{
    int gid = blockIdx.x * 256 + threadIdx.x;
    int d = gid & (D_INNER - 1);
    int rest = gid >> 11;
    int b = rest & 3;
    int ch = rest >> 2;          // 0..31
    int t0 = ch * 64;
    float w0 = cw[d * 4 + 0], w1 = cw[d * 4 + 1], w2 = cw[d * 4 + 2], w3 = cw[d * 4 + 3];
    float bias = cb[d];
    const __hip_bfloat16* base = xin + (size_t)b * SEQ * D_INNER + d;
    __hip_bfloat16* ob = xp + (size_t)b * SEQ * D_INNER + d;
    float xm3 = (t0 >= 3) ? __bfloat162float(base[(size_t)(t0 - 3) * D_INNER]) : 0.f;
    float xm2 = (t0 >= 2) ? __bfloat162float(base[(size_t)(t0 - 2) * D_INNER]) : 0.f;
    float xm1 = (t0 >= 1) ? __bfloat162float(base[(size_t)(t0 - 1) * D_INNER]) : 0.f;
#pragma unroll 4
    for (int t = t0; t < t0 + 64; ++t) {
        float xcur = __bfloat162float(base[(size_t)t * D_INNER]);
        float v = bias + w0 * xm3 + w1 * xm2 + w2 * xm1 + w3 * xcur;
        float sv = v / (1.f + __expf(-v));
        ob[(size_t)t * D_INNER] = __float2bfloat16(sv);
        xm3 = xm2; xm2 = xm1; xm1 = xcur;
    }
}

// ------------------------------------------------------------ chunked scan
// One thread owns ALL 16 states of one (b, d, chunk). No cross-lane ops.
// gid: d = low 11 bits (coalesced dt/xt/z access), ch next 4, b top 2.
// B/C rows are wave-uniform (same address across lanes) -> broadcast loads.

// pass 1: local scan from h=0; store final local h and decay product P (bf16)
__global__ __launch_bounds__(256, 2) void scan_p1(
    const ushort* __restrict__ dtb, const ushort* __restrict__ xpb,
    const ushort* __restrict__ BC, const float* __restrict__ A_log,
    ushort* __restrict__ hloc, ushort* __restrict__ prod)
{
    int gid = blockIdx.x * 256 + threadIdx.x;   // 131072
    int d  = gid & (D_INNER - 1);
    int ch = (gid >> 11) & (NCH - 1);
    int b  = gid >> 15;
    float A2[16];
    {
        const float4* Ar = (const float4*)(A_log + (size_t)d * D_STATE);
#pragma unroll
        for (int i = 0; i < 4; ++i) {
            float4 a = Ar[i];
            A2[4*i+0] = -__expf(a.x); A2[4*i+1] = -__expf(a.y);
            A2[4*i+2] = -__expf(a.z); A2[4*i+3] = -__expf(a.w);
        }
    }
    float h[16], P[16];
#pragma unroll
    for (int n = 0; n < 16; ++n) { h[n] = 0.f; P[n] = 1.f; }
    size_t mBase = (size_t)b * SEQ + (size_t)ch * TC;
    const ushort* dtp = dtb + mBase * D_INNER + d;
    const ushort* xpp = xpb + mBase * D_INNER + d;
    const uint4*  bcp = (const uint4*)(BC + mBase * 32);
    for (int t = 0; t < TC; ++t) {
        float dt = us2f(dtp[(size_t)t * D_INNER]);
        float xt = us2f(xpp[(size_t)t * D_INNER]);
        uint4 r0 = bcp[t * 4 + 0];
        uint4 r1 = bcp[t * 4 + 1];
        float Bv[16];
        unpack8(r0, Bv); unpack8(r1, Bv + 8);
        float dtx = dt * xt;
#pragma unroll
        for (int n = 0; n < 16; ++n) {
            float e = __expf(dt * A2[n]);
            h[n] = e * h[n] + dtx * Bv[n];
            P[n] *= e;
        }
    }
    size_t idx = ((size_t)(b * NCH + ch) * D_INNER + d) * D_STATE;
    uint4 ho, h2, po, p2;
    ho.x = pk2(h[0], h[1]);  ho.y = pk2(h[2], h[3]);
    ho.z = pk2(h[4], h[5]);  ho.w = pk2(h[6], h[7]);
    h2.x = pk2(h[8], h[9]);  h2.y = pk2(h[10], h[11]);
    h2.z = pk2(h[12], h[13]); h2.w = pk2(h[14], h[15]);
    po.x = pk2(P[0], P[1]);  po.y = pk2(P[2], P[3]);
    po.z = pk2(P[4], P[5]);  po.w = pk2(P[6], P[7]);
    p2.x = pk2(P[8], P[9]);  p2.y = pk2(P[10], P[11]);
    p2.z = pk2(P[12], P[13]); p2.w = pk2(P[14], P[15]);
    ((uint4*)(hloc + idx))[0] = ho; ((uint4*)(hloc + idx))[1] = h2;
    ((uint4*)(prod + idx))[0] = po; ((uint4*)(prod + idx))[1] = p2;
}

// pass 1.5: sequential combine over chunks; hloc becomes h_in per chunk
__global__ __launch_bounds__(256) void scan_mid(
    ushort* __restrict__ hloc, const ushort* __restrict__ prod)
{
    int gid = blockIdx.x * 256 + threadIdx.x;   // 131072 = b(2) d(11) n(4), n fastest
    int n = gid & 15, d = (gid >> 4) & (D_INNER - 1), b = gid >> 15;
    float h = 0.f;
#pragma unroll
    for (int ch = 0; ch < NCH; ++ch) {
        size_t idx = ((size_t)(b * NCH + ch) * D_INNER + d) * D_STATE + n;
        float old = us2f(hloc[idx]);
        float p   = us2f(prod[idx]);
        hloc[idx] = bf2us(h);
        h = old + p * h;
    }
}

// pass 2: rerun recurrence with correct h_in; yz = (C.h + D*x) * silu(z) in-place
__global__ __launch_bounds__(256, 2) void scan_p2(
    const ushort* __restrict__ dtb, const ushort* __restrict__ xpb,
    const ushort* __restrict__ BC, const float* __restrict__ A_log,
    const float* __restrict__ D_param, const ushort* __restrict__ hin,
    ushort* __restrict__ zio)
{
    int gid = blockIdx.x * 256 + threadIdx.x;
    int d  = gid & (D_INNER - 1);
    int ch = (gid >> 11) & (NCH - 1);
    int b  = gid >> 15;
    float A2[16];
    {
        const float4* Ar = (const float4*)(A_log + (size_t)d * D_STATE);
#pragma unroll
        for (int i = 0; i < 4; ++i) {
            float4 a = Ar[i];
            A2[4*i+0] = -__expf(a.x); A2[4*i+1] = -__expf(a.y);
            A2[4*i+2] = -__expf(a.z); A2[4*i+3] = -__expf(a.w);
        }
    }
    float Dp = D_param[d];
    float h[16];
    size_t idx = ((size_t)(b * NCH + ch) * D_INNER + d) * D_STATE;
    {
        uint4 r0 = ((const uint4*)(hin + idx))[0];
        uint4 r1 = ((const uint4*)(hin + idx))[1];
        unpack8(r0, h); unpack8(r1, h + 8);
    }
    size_t mBase = (size_t)b * SEQ + (size_t)ch * TC;
    const ushort* dtp = dtb + mBase * D_INNER + d;
    const ushort* xpp = xpb + mBase * D_INNER + d;
    const uint4*  bcp = (const uint4*)(BC + mBase * 32);
    ushort* zp = zio + mBase * D_INNER + d;
    for (int t = 0; t < TC; ++t) {
        float dt = us2f(dtp[(size_t)t * D_INNER]);
        float xt = us2f(xpp[(size_t)t * D_INNER]);
        uint4 r0 = bcp[t * 4 + 0];
        uint4 r1 = bcp[t * 4 + 1];
        uint4 r2 = bcp[t * 4 + 2];
        uint4 r3 = bcp[t * 4 + 3];
        float Bv[16], Cv[16];
        unpack8(r0, Bv); unpack8(r1, Bv + 8);
        unpack8(r2, Cv); unpack8(r3, Cv + 8);
        float dtx = dt * xt;
        float y = Dp * xt;
#pragma unroll
        for (int n = 0; n < 16; ++n) {
            float e = __expf(dt * A2[n]);
            h[n] = e * h[n] + dtx * Bv[n];
            y += h[n] * Cv[n];
        }
        float z = us2f(zp[(size_t)t * D_INNER]);
        zp[(size_t)t * D_INNER] = bf2us(y * z);
    }
}

// ------------------------------------------------------------------ launch
extern "C" void kernel_launch(void* const* d_in, const int* in_sizes, int n_in,
                              void* d_out, int out_size, void* d_ws, size_t ws_size,
                              hipStream_t stream)
{
    const float* x       = (const float*)d_in[0];
    const float* norm_w  = (const float*)d_in[1];
    const float* norm_b  = (const float*)d_in[2];
    const float* W_in    = (const float*)d_in[3];
    const float* conv_w  = (const float*)d_in[4];
    const float* conv_b  = (const float*)d_in[5];
    const float* A_log   = (const float*)d_in[6];
    const float* W_b     = (const float*)d_in[7];
    const float* W_c     = (const float*)d_in[8];
    const float* W_delta = (const float*)d_in[9];
    const float* b_delta = (const float*)d_in[10];
    const float* D_param = (const float*)d_in[11];
    const float* W_out   = (const float*)d_in[12];
    float* out = (float*)d_out;

    // ---- workspace: EXACTLY the proven 110,100,480-byte footprint (R2 lesson:
    //      210 MB overflowed d_ws and corrupted pristine inputs).
    char* ws = (char*)d_ws;
    char* R1 = ws;                          // 33,554,432
    char* R2 = R1 + (size_t)33554432;       // 33,554,432
    char* R3 = R2 + (size_t)33554432;       // 33,554,432
    char* R4 = R3 + (size_t)33554432;       //  8,912,896
    char* R5 = R4 + (size_t)8912896;        //    524,288  => 110,100,480

    // lifetimes:
    __hip_bfloat16* xnb  = (__hip_bfloat16*)R1;                 // ln .. gemm1
    __hip_bfloat16* wT1  = (__hip_bfloat16*)(R1 + 16777216);    // trW_in .. gemm1
    __hip_bfloat16* xp   = (__hip_bfloat16*)R1;                 // conv .. scan_p2
    __hip_bfloat16* xraw = (__hip_bfloat16*)R2;                 // gemm1 .. conv
    __hip_bfloat16* dtb  = (__hip_bfloat16*)R2;                 // gemm2 (softplus'd dt) .. scan_p2
    __hip_bfloat16* wT3  = (__hip_bfloat16*)R2;                 // trW_out .. gemm3 (over dead dtb)
    __hip_bfloat16* zio  = (__hip_bfloat16*)R3;                 // silu(z) then yz in-place
    __hip_bfloat16* wT2  = (__hip_bfloat16*)R4;                 // tr .. gemm2 (2176x2048)
    ushort*         hloc = (ushort*)R4;                         // scan_p1.. (4.19 MB, over dead wT2)
    ushort*         prodb= (ushort*)(R4 + 4194304);             // scan_p1.. (4.19 MB)
    __hip_bfloat16* BCb  = (__hip_bfloat16*)R5;                 // gemm2 .. scan (B|C rows)

    // 1. LayerNorm -> bf16
    ln_kernel<<<NTOK, 256, 0, stream>>>(x, norm_w, norm_b, xnb);

    // 2. W_in^T -> wT1
    transpose_cast<<<dim3(128, 32), dim3(32, 8), 0, stream>>>(W_in, wT1, 1024, 4096, 1024, 0);

    // 3. xz = xn @ W_in -> xraw (x-path) + silu(z) -> zio
    gemm_bt<1><<<dim3(NTOK / 128, 4096 / 128), 256, 0, stream>>>(
        xnb, wT1, NTOK, 4096, 1024, nullptr, xraw, zio, nullptr);

    // 4. [W_delta | W_b | W_c | 0]^T -> wT2
    transpose_cast<<<dim3(64, 64), dim3(32, 8), 0, stream>>>(W_delta, wT2, 2048, 2048, 2048, 0);
    transpose_cast<<<dim3(1, 64),  dim3(32, 8), 0, stream>>>(W_b,     wT2, 2048, 16,   2048, 2048);
    transpose_cast<<<dim3(1, 64),  dim3(32, 8), 0, stream>>>(W_c,     wT2, 2048, 16,   2048, 2064);
    zero_fill<<<96, 256, 0, stream>>>((uint4*)(wT2 + (size_t)2080 * 2048), 24576);

    // 5. conv + silu: xraw -> xp
    conv_silu<<<1024, 256, 0, stream>>>(xraw, conv_w, conv_b, xp);

    // 6. gemm2: dt = softplus(xp@W_delta + b_delta) -> dtb ; B|C -> BCb
    gemm_bt<2><<<dim3(NTOK / 128, NBIG / 128), 256, 0, stream>>>(
        xp, wT2, NTOK, NBIG, 2048, nullptr, dtb, BCb, b_delta);

    // 7. chunked scan, 16 states per thread
    scan_p1<<<512, 256, 0, stream>>>((const ushort*)dtb, (const ushort*)xp,
                                     (const ushort*)BCb, A_log, hloc, prodb);
    scan_mid<<<512, 256, 0, stream>>>(hloc, prodb);
    scan_p2<<<512, 256, 0, stream>>>((const ushort*)dtb, (const ushort*)xp,
                                     (const ushort*)BCb, A_log, D_param, hloc,
                                     (ushort*)zio);

    // 8. W_out^T -> wT3 (dtb region dead after scan_p2)
    transpose_cast<<<dim3(32, 64), dim3(32, 8), 0, stream>>>(W_out, wT3, 2048, 1024, 2048, 0);

    // 9. out = yz @ W_out + residual
    gemm_bt<3><<<dim3(NTOK / 128, D_MODEL / 128), 256, 0, stream>>>(
        zio, wT3, NTOK, D_MODEL, 2048, out, nullptr, nullptr, x);

    (void)in_sizes; (void)n_in; (void)out_size; (void)ws_size;
}

// Round 6
// 625.071 us; speedup vs baseline: 1.6953x; 1.1747x over previous
//
#include <hip/hip_runtime.h>
#include <hip/hip_bf16.h>

#define D_MODEL 1024
#define D_STATE 16
#define D_INNER 2048
#define BSZ     4
#define SEQ     2048
#define NTOK    (BSZ*SEQ)     /* 8192 tokens */
#define NBIG    2176          /* 2048 (delta) + 16 (B) + 16 (C) + pad to 17*128 */
#define NCH     16            /* scan chunks per sequence */
#define TC      128           /* scan chunk length */

typedef __attribute__((ext_vector_type(8))) short short8;
typedef __attribute__((ext_vector_type(4))) float floatx4;

__device__ __forceinline__ ushort bf2us(float f)
{
    union { __hip_bfloat16 h; ushort u; } c;
    c.h = __float2bfloat16(f);
    return c.u;
}
__device__ __forceinline__ float us2f(ushort u)
{
    union { uint u; float f; } c;
    c.u = ((uint)u) << 16;
    return c.f;
}
__device__ __forceinline__ uint pk2(float a, float b)
{
    return (uint)bf2us(a) | ((uint)bf2us(b) << 16);
}
__device__ __forceinline__ float blo(uint u) { return __uint_as_float(u << 16); }
__device__ __forceinline__ float bhi(uint u) { return __uint_as_float(u & 0xffff0000u); }
__device__ __forceinline__ float softplus_f(float v)
{
    return (v > 20.f) ? v : __logf(1.f + __expf(v));
}

// ---------------------------------------------------------------- LayerNorm
__global__ __launch_bounds__(256) void ln_kernel(
    const float* __restrict__ x, const float* __restrict__ w,
    const float* __restrict__ bvec, __hip_bfloat16* __restrict__ out)
{
    int token = blockIdx.x;
    int tid = threadIdx.x;
    const float4 v = ((const float4*)(x + (size_t)token * D_MODEL))[tid];
    float s  = v.x + v.y + v.z + v.w;
    float sq = v.x*v.x + v.y*v.y + v.z*v.z + v.w*v.w;
#pragma unroll
    for (int o = 32; o; o >>= 1) { s += __shfl_down(s, o, 64); sq += __shfl_down(sq, o, 64); }
    __shared__ float red[8];
    int wid = tid >> 6;
    if ((tid & 63) == 0) { red[wid] = s; red[wid + 4] = sq; }
    __syncthreads();
    s  = red[0] + red[1] + red[2] + red[3];
    sq = red[4] + red[5] + red[6] + red[7];
    float mu  = s * (1.f / D_MODEL);
    float var = sq * (1.f / D_MODEL) - mu * mu;
    float rs  = rsqrtf(var + 1e-5f);
    float4 wv = ((const float4*)w)[tid];
    float4 bv = ((const float4*)bvec)[tid];
    union { ushort4 u; __hip_bfloat16 h[4]; } p;
    p.h[0] = __float2bfloat16((v.x - mu) * rs * wv.x + bv.x);
    p.h[1] = __float2bfloat16((v.y - mu) * rs * wv.y + bv.y);
    p.h[2] = __float2bfloat16((v.z - mu) * rs * wv.z + bv.z);
    p.h[3] = __float2bfloat16((v.w - mu) * rs * wv.w + bv.w);
    ((ushort4*)(out + (size_t)token * D_MODEL))[tid] = p.u;
}

// ------------------------------------------------- transpose + cast fp32->bf16
__global__ __launch_bounds__(256) void transpose_cast(
    const float* __restrict__ src, __hip_bfloat16* __restrict__ dst,
    int R, int C, int dstStride, int dstRowOff)
{
    __shared__ float tile[32][33];
    int tx = threadIdx.x, ty = threadIdx.y;  // 32 x 8
    int bx = blockIdx.x, by = blockIdx.y;
#pragma unroll
    for (int i = 0; i < 4; ++i) {
        int r = by * 32 + ty + i * 8;
        int c = bx * 32 + tx;
        if (r < R && c < C) tile[ty + i * 8][tx] = src[(size_t)r * C + c];
    }
    __syncthreads();
#pragma unroll
    for (int i = 0; i < 4; ++i) {
        int c = bx * 32 + ty + i * 8;
        int r = by * 32 + tx;
        if (c < C && r < R)
            dst[(size_t)(dstRowOff + c) * dstStride + r] = __float2bfloat16(tile[tx][ty + i * 8]);
    }
}

__global__ __launch_bounds__(256) void zero_fill(uint4* __restrict__ p, int n)
{
    int i = blockIdx.x * 256 + threadIdx.x;
    if (i < n) { uint4 z = {0, 0, 0, 0}; p[i] = z; }
}

// ---------------------------------------------------------------- bf16 GEMM
// C[M,N] = A[M,K] * BT[N,K]^T ; 128x128 tile, BK=64, 4 waves of 64x64.
// MODE 1: cols<2048 -> outB1 (x-path) bf16 ; cols>=2048 -> silu -> outB2 bf16
// MODE 2: cols<2048 -> outB1 bf16 = softplus(v + extra[col])   (dt, final)
//         2048<=col<2080 -> outB2[row*32 + col-2048] bf16 (B|C); col>=2080 dropped
// MODE 3: outF[row*1024+col] = v + extra[row*1024+col]  (residual add)
template <int MODE>
__global__ __launch_bounds__(256) void gemm_bt(
    const __hip_bfloat16* __restrict__ A, const __hip_bfloat16* __restrict__ BT,
    int M, int N, int K,
    float* __restrict__ outF,
    __hip_bfloat16* __restrict__ outB1, __hip_bfloat16* __restrict__ outB2,
    const float* __restrict__ extra)
{
    __shared__ __align__(16) __hip_bfloat16 As[128 * 72];
    __shared__ __align__(16) __hip_bfloat16 Bs[128 * 72];
    int tid = threadIdx.x;
    int m0 = blockIdx.x * 128;
    int n0 = blockIdx.y * 128;
    int wid = tid >> 6, lane = tid & 63;
    int wm = (wid >> 1) * 64, wn = (wid & 1) * 64;
    int lr = lane & 15, lq = lane >> 4;

    floatx4 acc[4][4] = {};

    for (int k0 = 0; k0 < K; k0 += 64) {
        __syncthreads();
#pragma unroll
        for (int i = 0; i < 4; ++i) {
            int linear = (i * 256 + tid) * 8;
            int row = linear >> 6, col = linear & 63;
            *(int4*)(As + row * 72 + col) = *(const int4*)(A  + (size_t)(m0 + row) * K + k0 + col);
            *(int4*)(Bs + row * 72 + col) = *(const int4*)(BT + (size_t)(n0 + row) * K + k0 + col);
        }
        __syncthreads();
#pragma unroll
        for (int kk = 0; kk < 2; ++kk) {
            short8 af[4], bf[4];
#pragma unroll
            for (int mi = 0; mi < 4; ++mi)
                af[mi] = *(const short8*)(As + (wm + mi * 16 + lr) * 72 + kk * 32 + lq * 8);
#pragma unroll
            for (int ni = 0; ni < 4; ++ni)
                bf[ni] = *(const short8*)(Bs + (wn + ni * 16 + lr) * 72 + kk * 32 + lq * 8);
#pragma unroll
            for (int mi = 0; mi < 4; ++mi)
#pragma unroll
                for (int ni = 0; ni < 4; ++ni)
                    acc[mi][ni] = __builtin_amdgcn_mfma_f32_16x16x32_bf16(af[mi], bf[ni], acc[mi][ni], 0, 0, 0);
        }
    }

#pragma unroll
    for (int mi = 0; mi < 4; ++mi)
#pragma unroll
        for (int ni = 0; ni < 4; ++ni)
#pragma unroll
            for (int r = 0; r < 4; ++r) {
                int rg = m0 + wm + mi * 16 + lq * 4 + r;
                int cg = n0 + wn + ni * 16 + lr;
                float v = acc[mi][ni][r];
                if (MODE == 1) {
                    if (cg < D_INNER) {
                        outB1[(size_t)rg * D_INNER + cg] = __float2bfloat16(v);
                    } else {
                        float sv = v / (1.f + __expf(-v));
                        outB2[(size_t)rg * D_INNER + (cg - D_INNER)] = __float2bfloat16(sv);
                    }
                } else if (MODE == 2) {
                    if (cg < D_INNER) {
                        outB1[(size_t)rg * D_INNER + cg] = __float2bfloat16(softplus_f(v + extra[cg]));
                    } else if (cg < D_INNER + 32) {
                        outB2[(size_t)rg * 32 + (cg - D_INNER)] = __float2bfloat16(v);
                    }
                } else {
                    outF[(size_t)rg * D_MODEL + cg] = v + extra[(size_t)rg * D_MODEL + cg];
                }
            }
}

// ------------------------------------------- depthwise causal conv (K=4) + SiLU
__global__ __launch_bounds__(256) void conv_silu(
    const __hip_bfloat16* __restrict__ xin, const float* __restrict__ cw,
    const float* __restrict__ cb, __hip_bfloat16* __restrict__ xp)
{
    int gid = blockIdx.x * 256 + threadIdx.x;
    int d = gid & (D_INNER - 1);
    int rest = gid >> 11;
    int b = rest & 3;
    int ch = rest >> 2;          // 0..31
    int t0 = ch * 64;
    float w0 = cw[d * 4 + 0], w1 = cw[d * 4 + 1], w2 = cw[d * 4 + 2], w3 = cw[d * 4 + 3];
    float bias = cb[d];
    const __hip_bfloat16* base = xin + (size_t)b * SEQ * D_INNER + d;
    __hip_bfloat16* ob = xp + (size_t)b * SEQ * D_INNER + d;
    float xm3 = (t0 >= 3) ? __bfloat162float(base[(size_t)(t0 - 3) * D_INNER]) : 0.f;
    float xm2 = (t0 >= 2) ? __bfloat162float(base[(size_t)(t0 - 2) * D_INNER]) : 0.f;
    float xm1 = (t0 >= 1) ? __bfloat162float(base[(size_t)(t0 - 1) * D_INNER]) : 0.f;
#pragma unroll 4
    for (int t = t0; t < t0 + 64; ++t) {
        float xcur = __bfloat162float(base[(size_t)t * D_INNER]);
        float v = bias + w0 * xm3 + w1 * xm2 + w2 * xm1 + w3 * xcur;
        float sv = v / (1.f + __expf(-v));
        ob[(size_t)t * D_INNER] = __float2bfloat16(sv);
        xm3 = xm2; xm2 = xm1; xm1 = xcur;
    }
}

// ------------------------------------------------------------ chunked scan
// One thread owns ALL 16 states of one (b, d, chunk). NO local arrays —
// everything is named scalars (R5 lesson: arrays + pointer-arg unpack helper
// -> scratch spill, VGPR_Count=40, 3260 cyc/iter).
// gid: d = low 11 bits (coalesced dt/xt/z), ch next 4, b top 2.

#define LOAD_A16() \
    const float4* Ar = (const float4*)(A_log + (size_t)d * D_STATE); \
    float4 aA = Ar[0], aB = Ar[1], aC = Ar[2], aD = Ar[3]; \
    float A0 = -__expf(aA.x), A1 = -__expf(aA.y), A2 = -__expf(aA.z), A3 = -__expf(aA.w); \
    float A4 = -__expf(aB.x), A5 = -__expf(aB.y), A6 = -__expf(aB.z), A7 = -__expf(aB.w); \
    float A8 = -__expf(aC.x), A9 = -__expf(aC.y), A10 = -__expf(aC.z), A11 = -__expf(aC.w); \
    float A12 = -__expf(aD.x), A13 = -__expf(aD.y), A14 = -__expf(aD.z), A15 = -__expf(aD.w)

#define UNPACK16(P, r0, r1) \
    float P##0 = blo(r0.x), P##1 = bhi(r0.x), P##2 = blo(r0.y), P##3 = bhi(r0.y); \
    float P##4 = blo(r0.z), P##5 = bhi(r0.z), P##6 = blo(r0.w), P##7 = bhi(r0.w); \
    float P##8 = blo(r1.x), P##9 = bhi(r1.x), P##10 = blo(r1.y), P##11 = bhi(r1.y); \
    float P##12 = blo(r1.z), P##13 = bhi(r1.z), P##14 = blo(r1.w), P##15 = bhi(r1.w)

// pass 1: local scan from h=0; store final local h and decay product P.
// P_n = prod_t exp(dt_t*A_n) = exp(A_n * sum_t dt_t)  (exact) -> one dtsum.
__global__ __launch_bounds__(256) void scan_p1(
    const ushort* __restrict__ dtb, const ushort* __restrict__ xpb,
    const ushort* __restrict__ BC, const float* __restrict__ A_log,
    ushort* __restrict__ hloc, ushort* __restrict__ prod)
{
    int gid = blockIdx.x * 256 + threadIdx.x;   // 131072
    int d  = gid & (D_INNER - 1);
    int ch = (gid >> 11) & (NCH - 1);
    int b  = gid >> 15;
    LOAD_A16();
    float h0 = 0.f, h1 = 0.f, h2 = 0.f, h3 = 0.f, h4 = 0.f, h5 = 0.f, h6 = 0.f, h7 = 0.f;
    float h8 = 0.f, h9 = 0.f, h10 = 0.f, h11 = 0.f, h12 = 0.f, h13 = 0.f, h14 = 0.f, h15 = 0.f;
    float dtsum = 0.f;
    size_t mBase = (size_t)b * SEQ + (size_t)ch * TC;
    const ushort* dtp = dtb + mBase * D_INNER + d;
    const ushort* xpp = xpb + mBase * D_INNER + d;
    const uint4*  bcp = (const uint4*)(BC + mBase * 32);
    for (int t = 0; t < TC; ++t) {
        float dt = us2f(dtp[(size_t)t * D_INNER]);
        float xt = us2f(xpp[(size_t)t * D_INNER]);
        uint4 r0 = bcp[t * 4 + 0];
        uint4 r1 = bcp[t * 4 + 1];
        float dtx = dt * xt;
        dtsum += dt;
        UNPACK16(B, r0, r1);
        h0  = __expf(dt * A0)  * h0  + dtx * B0;
        h1  = __expf(dt * A1)  * h1  + dtx * B1;
        h2  = __expf(dt * A2)  * h2  + dtx * B2;
        h3  = __expf(dt * A3)  * h3  + dtx * B3;
        h4  = __expf(dt * A4)  * h4  + dtx * B4;
        h5  = __expf(dt * A5)  * h5  + dtx * B5;
        h6  = __expf(dt * A6)  * h6  + dtx * B6;
        h7  = __expf(dt * A7)  * h7  + dtx * B7;
        h8  = __expf(dt * A8)  * h8  + dtx * B8;
        h9  = __expf(dt * A9)  * h9  + dtx * B9;
        h10 = __expf(dt * A10) * h10 + dtx * B10;
        h11 = __expf(dt * A11) * h11 + dtx * B11;
        h12 = __expf(dt * A12) * h12 + dtx * B12;
        h13 = __expf(dt * A13) * h13 + dtx * B13;
        h14 = __expf(dt * A14) * h14 + dtx * B14;
        h15 = __expf(dt * A15) * h15 + dtx * B15;
    }
    size_t idx = ((size_t)(b * NCH + ch) * D_INNER + d) * D_STATE;
    uint4 ho, h2v, po, p2v;
    ho.x  = pk2(h0, h1);   ho.y  = pk2(h2, h3);
    ho.z  = pk2(h4, h5);   ho.w  = pk2(h6, h7);
    h2v.x = pk2(h8, h9);   h2v.y = pk2(h10, h11);
    h2v.z = pk2(h12, h13); h2v.w = pk2(h14, h15);
    po.x  = pk2(__expf(dtsum * A0),  __expf(dtsum * A1));
    po.y  = pk2(__expf(dtsum * A2),  __expf(dtsum * A3));
    po.z  = pk2(__expf(dtsum * A4),  __expf(dtsum * A5));
    po.w  = pk2(__expf(dtsum * A6),  __expf(dtsum * A7));
    p2v.x = pk2(__expf(dtsum * A8),  __expf(dtsum * A9));
    p2v.y = pk2(__expf(dtsum * A10), __expf(dtsum * A11));
    p2v.z = pk2(__expf(dtsum * A12), __expf(dtsum * A13));
    p2v.w = pk2(__expf(dtsum * A14), __expf(dtsum * A15));
    ((uint4*)(hloc + idx))[0] = ho; ((uint4*)(hloc + idx))[1] = h2v;
    ((uint4*)(prod + idx))[0] = po; ((uint4*)(prod + idx))[1] = p2v;
}

// pass 1.5: sequential combine over chunks; hloc becomes h_in per chunk
__global__ __launch_bounds__(256) void scan_mid(
    ushort* __restrict__ hloc, const ushort* __restrict__ prod)
{
    int gid = blockIdx.x * 256 + threadIdx.x;   // 131072 = b(2) d(11) n(4), n fastest
    int n = gid & 15, d = (gid >> 4) & (D_INNER - 1), b = gid >> 15;
    float h = 0.f;
#pragma unroll
    for (int ch = 0; ch < NCH; ++ch) {
        size_t idx = ((size_t)(b * NCH + ch) * D_INNER + d) * D_STATE + n;
        float old = us2f(hloc[idx]);
        float p   = us2f(prod[idx]);
        hloc[idx] = bf2us(h);
        h = old + p * h;
    }
}

// pass 2: rerun recurrence with correct h_in; yz = (C.h + D*x) * silu(z) in-place
__global__ __launch_bounds__(256) void scan_p2(
    const ushort* __restrict__ dtb, const ushort* __restrict__ xpb,
    const ushort* __restrict__ BC, const float* __restrict__ A_log,
    const float* __restrict__ D_param, const ushort* __restrict__ hin,
    ushort* __restrict__ zio)
{
    int gid = blockIdx.x * 256 + threadIdx.x;
    int d  = gid & (D_INNER - 1);
    int ch = (gid >> 11) & (NCH - 1);
    int b  = gid >> 15;
    LOAD_A16();
    float Dp = D_param[d];
    size_t idx = ((size_t)(b * NCH + ch) * D_INNER + d) * D_STATE;
    uint4 hr0 = ((const uint4*)(hin + idx))[0];
    uint4 hr1 = ((const uint4*)(hin + idx))[1];
    float h0 = blo(hr0.x), h1 = bhi(hr0.x), h2 = blo(hr0.y), h3 = bhi(hr0.y);
    float h4 = blo(hr0.z), h5 = bhi(hr0.z), h6 = blo(hr0.w), h7 = bhi(hr0.w);
    float h8 = blo(hr1.x), h9 = bhi(hr1.x), h10 = blo(hr1.y), h11 = bhi(hr1.y);
    float h12 = blo(hr1.z), h13 = bhi(hr1.z), h14 = blo(hr1.w), h15 = bhi(hr1.w);
    size_t mBase = (size_t)b * SEQ + (size_t)ch * TC;
    const ushort* dtp = dtb + mBase * D_INNER + d;
    const ushort* xpp = xpb + mBase * D_INNER + d;
    const uint4*  bcp = (const uint4*)(BC + mBase * 32);
    ushort* zp = zio + mBase * D_INNER + d;
    for (int t = 0; t < TC; ++t) {
        float dt = us2f(dtp[(size_t)t * D_INNER]);
        float xt = us2f(xpp[(size_t)t * D_INNER]);
        uint4 r0 = bcp[t * 4 + 0];
        uint4 r1 = bcp[t * 4 + 1];
        uint4 r2 = bcp[t * 4 + 2];
        uint4 r3 = bcp[t * 4 + 3];
        UNPACK16(B, r0, r1);
        UNPACK16(C, r2, r3);
        float dtx = dt * xt;
        float y = Dp * xt;
        h0  = __expf(dt * A0)  * h0  + dtx * B0;   y += h0  * C0;
        h1  = __expf(dt * A1)  * h1  + dtx * B1;   y += h1  * C1;
        h2  = __expf(dt * A2)  * h2  + dtx * B2;   y += h2  * C2;
        h3  = __expf(dt * A3)  * h3  + dtx * B3;   y += h3  * C3;
        h4  = __expf(dt * A4)  * h4  + dtx * B4;   y += h4  * C4;
        h5  = __expf(dt * A5)  * h5  + dtx * B5;   y += h5  * C5;
        h6  = __expf(dt * A6)  * h6  + dtx * B6;   y += h6  * C6;
        h7  = __expf(dt * A7)  * h7  + dtx * B7;   y += h7  * C7;
        h8  = __expf(dt * A8)  * h8  + dtx * B8;   y += h8  * C8;
        h9  = __expf(dt * A9)  * h9  + dtx * B9;   y += h9  * C9;
        h10 = __expf(dt * A10) * h10 + dtx * B10;  y += h10 * C10;
        h11 = __expf(dt * A11) * h11 + dtx * B11;  y += h11 * C11;
        h12 = __expf(dt * A12) * h12 + dtx * B12;  y += h12 * C12;
        h13 = __expf(dt * A13) * h13 + dtx * B13;  y += h13 * C13;
        h14 = __expf(dt * A14) * h14 + dtx * B14;  y += h14 * C14;
        h15 = __expf(dt * A15) * h15 + dtx * B15;  y += h15 * C15;
        float z = us2f(zp[(size_t)t * D_INNER]);
        zp[(size_t)t * D_INNER] = bf2us(y * z);
    }
}

// ------------------------------------------------------------------ launch
extern "C" void kernel_launch(void* const* d_in, const int* in_sizes, int n_in,
                              void* d_out, int out_size, void* d_ws, size_t ws_size,
                              hipStream_t stream)
{
    const float* x       = (const float*)d_in[0];
    const float* norm_w  = (const float*)d_in[1];
    const float* norm_b  = (const float*)d_in[2];
    const float* W_in    = (const float*)d_in[3];
    const float* conv_w  = (const float*)d_in[4];
    const float* conv_b  = (const float*)d_in[5];
    const float* A_log   = (const float*)d_in[6];
    const float* W_b     = (const float*)d_in[7];
    const float* W_c     = (const float*)d_in[8];
    const float* W_delta = (const float*)d_in[9];
    const float* b_delta = (const float*)d_in[10];
    const float* D_param = (const float*)d_in[11];
    const float* W_out   = (const float*)d_in[12];
    float* out = (float*)d_out;

    // ---- workspace: EXACTLY the proven 110,100,480-byte footprint (R2 lesson:
    //      210 MB overflowed d_ws and corrupted pristine inputs).
    char* ws = (char*)d_ws;
    char* R1 = ws;                          // 33,554,432
    char* R2 = R1 + (size_t)33554432;       // 33,554,432
    char* R3 = R2 + (size_t)33554432;       // 33,554,432
    char* R4 = R3 + (size_t)33554432;       //  8,912,896
    char* R5 = R4 + (size_t)8912896;        //    524,288  => 110,100,480

    // lifetimes:
    __hip_bfloat16* xnb  = (__hip_bfloat16*)R1;                 // ln .. gemm1
    __hip_bfloat16* wT1  = (__hip_bfloat16*)(R1 + 16777216);    // trW_in .. gemm1
    __hip_bfloat16* xp   = (__hip_bfloat16*)R1;                 // conv .. scan_p2
    __hip_bfloat16* xraw = (__hip_bfloat16*)R2;                 // gemm1 .. conv
    __hip_bfloat16* dtb  = (__hip_bfloat16*)R2;                 // gemm2 (softplus'd dt) .. scan_p2
    __hip_bfloat16* wT3  = (__hip_bfloat16*)R2;                 // trW_out .. gemm3 (over dead dtb)
    __hip_bfloat16* zio  = (__hip_bfloat16*)R3;                 // silu(z) then yz in-place
    __hip_bfloat16* wT2  = (__hip_bfloat16*)R4;                 // tr .. gemm2 (2176x2048)
    ushort*         hloc = (ushort*)R4;                         // scan_p1.. (4.19 MB, over dead wT2)
    ushort*         prodb= (ushort*)(R4 + 4194304);             // scan_p1.. (4.19 MB)
    __hip_bfloat16* BCb  = (__hip_bfloat16*)R5;                 // gemm2 .. scan (B|C rows)

    // 1. LayerNorm -> bf16
    ln_kernel<<<NTOK, 256, 0, stream>>>(x, norm_w, norm_b, xnb);

    // 2. W_in^T -> wT1
    transpose_cast<<<dim3(128, 32), dim3(32, 8), 0, stream>>>(W_in, wT1, 1024, 4096, 1024, 0);

    // 3. xz = xn @ W_in -> xraw (x-path) + silu(z) -> zio
    gemm_bt<1><<<dim3(NTOK / 128, 4096 / 128), 256, 0, stream>>>(
        xnb, wT1, NTOK, 4096, 1024, nullptr, xraw, zio, nullptr);

    // 4. [W_delta | W_b | W_c | 0]^T -> wT2
    transpose_cast<<<dim3(64, 64), dim3(32, 8), 0, stream>>>(W_delta, wT2, 2048, 2048, 2048, 0);
    transpose_cast<<<dim3(1, 64),  dim3(32, 8), 0, stream>>>(W_b,     wT2, 2048, 16,   2048, 2048);
    transpose_cast<<<dim3(1, 64),  dim3(32, 8), 0, stream>>>(W_c,     wT2, 2048, 16,   2048, 2064);
    zero_fill<<<96, 256, 0, stream>>>((uint4*)(wT2 + (size_t)2080 * 2048), 24576);

    // 5. conv + silu: xraw -> xp
    conv_silu<<<1024, 256, 0, stream>>>(xraw, conv_w, conv_b, xp);

    // 6. gemm2: dt = softplus(xp@W_delta + b_delta) -> dtb ; B|C -> BCb
    gemm_bt<2><<<dim3(NTOK / 128, NBIG / 128), 256, 0, stream>>>(
        xp, wT2, NTOK, NBIG, 2048, nullptr, dtb, BCb, b_delta);

    // 7. chunked scan, 16 states per thread (all named scalars, no arrays)
    scan_p1<<<512, 256, 0, stream>>>((const ushort*)dtb, (const ushort*)xp,
                                     (const ushort*)BCb, A_log, hloc, prodb);
    scan_mid<<<512, 256, 0, stream>>>(hloc, prodb);
    scan_p2<<<512, 256, 0, stream>>>((const ushort*)dtb, (const ushort*)xp,
                                     (const ushort*)BCb, A_log, D_param, hloc,
                                     (ushort*)zio);

    // 8. W_out^T -> wT3 (dtb region dead after scan_p2)
    transpose_cast<<<dim3(32, 64), dim3(32, 8), 0, stream>>>(W_out, wT3, 2048, 1024, 2048, 0);

    // 9. out = yz @ W_out + residual
    gemm_bt<3><<<dim3(NTOK / 128, D_MODEL / 128), 256, 0, stream>>>(
        zio, wT3, NTOK, D_MODEL, 2048, out, nullptr, nullptr, x);

    (void)in_sizes; (void)n_in; (void)out_size; (void)ws_size;
}

// Round 7
// 582.453 us; speedup vs baseline: 1.8193x; 1.0732x over previous
//
#include <hip/hip_runtime.h>
#include <hip/hip_bf16.h>

#define D_MODEL 1024
#define D_STATE 16
#define D_INNER 2048
#define BSZ     4
#define SEQ     2048
#define NTOK    (BSZ*SEQ)     /* 8192 tokens */
#define NBIG    2176          /* 2048 (delta) + 16 (B) + 16 (C) + pad to 17*128 */
#define NCH     16            /* scan chunks per sequence */
#define TC      128           /* scan chunk length */

typedef __attribute__((ext_vector_type(8))) short short8;
typedef __attribute__((ext_vector_type(4))) float floatx4;

__device__ __forceinline__ ushort bf2us(float f)
{
    union { __hip_bfloat16 h; ushort u; } c;
    c.h = __float2bfloat16(f);
    return c.u;
}
__device__ __forceinline__ float us2f(ushort u)
{
    union { uint u; float f; } c;
    c.u = ((uint)u) << 16;
    return c.f;
}
__device__ __forceinline__ uint pk2(float a, float b)
{
    return (uint)bf2us(a) | ((uint)bf2us(b) << 16);
}
__device__ __forceinline__ float blo(uint u) { return __uint_as_float(u << 16); }
__device__ __forceinline__ float bhi(uint u) { return __uint_as_float(u & 0xffff0000u); }
__device__ __forceinline__ float softplus_f(float v)
{
    return (v > 20.f) ? v : __logf(1.f + __expf(v));
}

// async global->LDS, 16B per lane; LDS dest = wave-uniform base + lane*16
__device__ __forceinline__ void load_lds16(const __hip_bfloat16* g, __hip_bfloat16* l)
{
    __builtin_amdgcn_global_load_lds(
        (const __attribute__((address_space(1))) char*)g,
        (__attribute__((address_space(3))) char*)l, 16, 0, 0);
}

// ---------------------------------------------------------------- LayerNorm
__global__ __launch_bounds__(256) void ln_kernel(
    const float* __restrict__ x, const float* __restrict__ w,
    const float* __restrict__ bvec, __hip_bfloat16* __restrict__ out)
{
    int token = blockIdx.x;
    int tid = threadIdx.x;
    const float4 v = ((const float4*)(x + (size_t)token * D_MODEL))[tid];
    float s  = v.x + v.y + v.z + v.w;
    float sq = v.x*v.x + v.y*v.y + v.z*v.z + v.w*v.w;
#pragma unroll
    for (int o = 32; o; o >>= 1) { s += __shfl_down(s, o, 64); sq += __shfl_down(sq, o, 64); }
    __shared__ float red[8];
    int wid = tid >> 6;
    if ((tid & 63) == 0) { red[wid] = s; red[wid + 4] = sq; }
    __syncthreads();
    s  = red[0] + red[1] + red[2] + red[3];
    sq = red[4] + red[5] + red[6] + red[7];
    float mu  = s * (1.f / D_MODEL);
    float var = sq * (1.f / D_MODEL) - mu * mu;
    float rs  = rsqrtf(var + 1e-5f);
    float4 wv = ((const float4*)w)[tid];
    float4 bv = ((const float4*)bvec)[tid];
    union { ushort4 u; __hip_bfloat16 h[4]; } p;
    p.h[0] = __float2bfloat16((v.x - mu) * rs * wv.x + bv.x);
    p.h[1] = __float2bfloat16((v.y - mu) * rs * wv.y + bv.y);
    p.h[2] = __float2bfloat16((v.z - mu) * rs * wv.z + bv.z);
    p.h[3] = __float2bfloat16((v.w - mu) * rs * wv.w + bv.w);
    ((ushort4*)(out + (size_t)token * D_MODEL))[tid] = p.u;
}

// ------------------------------------------------- transpose + cast fp32->bf16
__global__ __launch_bounds__(256) void transpose_cast(
    const float* __restrict__ src, __hip_bfloat16* __restrict__ dst,
    int R, int C, int dstStride, int dstRowOff)
{
    __shared__ float tile[32][33];
    int tx = threadIdx.x, ty = threadIdx.y;  // 32 x 8
    int bx = blockIdx.x, by = blockIdx.y;
#pragma unroll
    for (int i = 0; i < 4; ++i) {
        int r = by * 32 + ty + i * 8;
        int c = bx * 32 + tx;
        if (r < R && c < C) tile[ty + i * 8][tx] = src[(size_t)r * C + c];
    }
    __syncthreads();
#pragma unroll
    for (int i = 0; i < 4; ++i) {
        int c = bx * 32 + ty + i * 8;
        int r = by * 32 + tx;
        if (c < C && r < R)
            dst[(size_t)(dstRowOff + c) * dstStride + r] = __float2bfloat16(tile[tx][ty + i * 8]);
    }
}

__global__ __launch_bounds__(256) void zero_fill(uint4* __restrict__ p, int n)
{
    int i = blockIdx.x * 256 + threadIdx.x;
    if (i < n) { uint4 z = {0, 0, 0, 0}; p[i] = z; }
}

// ---------------------------------------------------------------- bf16 GEMM
// C[M,N] = A[M,K] * BT[N,K]^T ; 128x128 tile, BK=64, 4 waves of 64x64.
// Staging: global_load_lds width=16 (m97 ladder step), unpadded stride-64
// LDS tiles with XOR swizzle phys_cg = cg ^ (row&7) (bank-conflict-free:
// unpadded stride-64 alone would 4-way-alias ds_read_b128).
// MODE 1: cols<2048 -> outB1 (x-path) bf16 ; cols>=2048 -> silu -> outB2 bf16
// MODE 2: cols<2048 -> outB1 bf16 = softplus(v + extra[col])   (dt, final)
//         2048<=col<2080 -> outB2[row*32 + col-2048] bf16 (B|C); col>=2080 dropped
// MODE 3: outF[row*1024+col] = v + extra[row*1024+col]  (residual add)
template <int MODE>
__global__ __launch_bounds__(256) void gemm_bt(
    const __hip_bfloat16* __restrict__ A, const __hip_bfloat16* __restrict__ BT,
    int M, int N, int K,
    float* __restrict__ outF,
    __hip_bfloat16* __restrict__ outB1, __hip_bfloat16* __restrict__ outB2,
    const float* __restrict__ extra)
{
    __shared__ __align__(16) __hip_bfloat16 As[128 * 64];
    __shared__ __align__(16) __hip_bfloat16 Bs[128 * 64];
    int tid = threadIdx.x;
    int m0 = blockIdx.x * 128;
    int n0 = blockIdx.y * 128;
    int wv = tid >> 6, lane = tid & 63;
    int wm = (wv >> 1) * 64, wn = (wv & 1) * 64;
    int lr = lane & 15, lq = lane >> 4;

    // staging addresses: lane covers tile row (i*32 + wv*8 + (lane>>3)),
    // fetching logical colgroup ((lane&7) ^ (lane>>3)) so that the HW's
    // contiguous lane*16B placement realizes the swizzled layout.
    int srow = wv * 8 + (lane >> 3);
    int scg  = (lane & 7) ^ (lane >> 3);
    const __hip_bfloat16* Ag = A  + (size_t)(m0 + srow) * K + scg * 8;
    const __hip_bfloat16* Bg = BT + (size_t)(n0 + srow) * K + scg * 8;
    __hip_bfloat16* AsW = As + (wv * 8) * 64;   // wave-uniform LDS dest (i=0)
    __hip_bfloat16* BsW = Bs + (wv * 8) * 64;

    // fragment-read swizzle: row&7 == lr&7 for all frag rows
    int swz = lq ^ (lr & 7);

    floatx4 acc[4][4] = {};

    for (int k0 = 0; k0 < K; k0 += 64) {
        __syncthreads();
#pragma unroll
        for (int i = 0; i < 4; ++i) {
            load_lds16(Ag + (size_t)(i * 32) * K + k0, AsW + i * 32 * 64);
            load_lds16(Bg + (size_t)(i * 32) * K + k0, BsW + i * 32 * 64);
        }
        __syncthreads();
#pragma unroll
        for (int kk = 0; kk < 2; ++kk) {
            int cofs = (swz ^ (kk << 2)) * 8;
            short8 af[4], bf[4];
#pragma unroll
            for (int mi = 0; mi < 4; ++mi)
                af[mi] = *(const short8*)(As + (wm + mi * 16 + lr) * 64 + cofs);
#pragma unroll
            for (int ni = 0; ni < 4; ++ni)
                bf[ni] = *(const short8*)(Bs + (wn + ni * 16 + lr) * 64 + cofs);
#pragma unroll
            for (int mi = 0; mi < 4; ++mi)
#pragma unroll
                for (int ni = 0; ni < 4; ++ni)
                    acc[mi][ni] = __builtin_amdgcn_mfma_f32_16x16x32_bf16(af[mi], bf[ni], acc[mi][ni], 0, 0, 0);
        }
    }

#pragma unroll
    for (int mi = 0; mi < 4; ++mi)
#pragma unroll
        for (int ni = 0; ni < 4; ++ni)
#pragma unroll
            for (int r = 0; r < 4; ++r) {
                int rg = m0 + wm + mi * 16 + lq * 4 + r;
                int cg = n0 + wn + ni * 16 + lr;
                float v = acc[mi][ni][r];
                if (MODE == 1) {
                    if (cg < D_INNER) {
                        outB1[(size_t)rg * D_INNER + cg] = __float2bfloat16(v);
                    } else {
                        float sv = v / (1.f + __expf(-v));
                        outB2[(size_t)rg * D_INNER + (cg - D_INNER)] = __float2bfloat16(sv);
                    }
                } else if (MODE == 2) {
                    if (cg < D_INNER) {
                        outB1[(size_t)rg * D_INNER + cg] = __float2bfloat16(softplus_f(v + extra[cg]));
                    } else if (cg < D_INNER + 32) {
                        outB2[(size_t)rg * 32 + (cg - D_INNER)] = __float2bfloat16(v);
                    }
                } else {
                    outF[(size_t)rg * D_MODEL + cg] = v + extra[(size_t)rg * D_MODEL + cg];
                }
            }
}

// ------------------------------------------- depthwise causal conv (K=4) + SiLU
__global__ __launch_bounds__(256) void conv_silu(
    const __hip_bfloat16* __restrict__ xin, const float* __restrict__ cw,
    const float* __restrict__ cb, __hip_bfloat16* __restrict__ xp)
{
    int gid = blockIdx.x * 256 + threadIdx.x;
    int d = gid & (D_INNER - 1);
    int rest = gid >> 11;
    int b = rest & 3;
    int ch = rest >> 2;          // 0..31
    int t0 = ch * 64;
    float w0 = cw[d * 4 + 0], w1 = cw[d * 4 + 1], w2 = cw[d * 4 + 2], w3 = cw[d * 4 + 3];
    float bias = cb[d];
    const __hip_bfloat16* base = xin + (size_t)b * SEQ * D_INNER + d;
    __hip_bfloat16* ob = xp + (size_t)b * SEQ * D_INNER + d;
    float xm3 = (t0 >= 3) ? __bfloat162float(base[(size_t)(t0 - 3) * D_INNER]) : 0.f;
    float xm2 = (t0 >= 2) ? __bfloat162float(base[(size_t)(t0 - 2) * D_INNER]) : 0.f;
    float xm1 = (t0 >= 1) ? __bfloat162float(base[(size_t)(t0 - 1) * D_INNER]) : 0.f;
#pragma unroll 4
    for (int t = t0; t < t0 + 64; ++t) {
        float xcur = __bfloat162float(base[(size_t)t * D_INNER]);
        float v = bias + w0 * xm3 + w1 * xm2 + w2 * xm1 + w3 * xcur;
        float sv = v / (1.f + __expf(-v));
        ob[(size_t)t * D_INNER] = __float2bfloat16(sv);
        xm3 = xm2; xm2 = xm1; xm1 = xcur;
    }
}

// ------------------------------------------------------------ chunked scan
// One thread owns ALL 16 states of one (b, d, chunk). NO local arrays —
// everything is named scalars (R5 lesson: arrays + pointer-arg unpack helper
// -> scratch spill, VGPR_Count=40, 3260 cyc/iter).
// gid: d = low 11 bits (coalesced dt/xt/z), ch next 4, b top 2.

#define LOAD_A16() \
    const float4* Ar = (const float4*)(A_log + (size_t)d * D_STATE); \
    float4 aA = Ar[0], aB = Ar[1], aC = Ar[2], aD = Ar[3]; \
    float A0 = -__expf(aA.x), A1 = -__expf(aA.y), A2 = -__expf(aA.z), A3 = -__expf(aA.w); \
    float A4 = -__expf(aB.x), A5 = -__expf(aB.y), A6 = -__expf(aB.z), A7 = -__expf(aB.w); \
    float A8 = -__expf(aC.x), A9 = -__expf(aC.y), A10 = -__expf(aC.z), A11 = -__expf(aC.w); \
    float A12 = -__expf(aD.x), A13 = -__expf(aD.y), A14 = -__expf(aD.z), A15 = -__expf(aD.w)

#define UNPACK16(P, r0, r1) \
    float P##0 = blo(r0.x), P##1 = bhi(r0.x), P##2 = blo(r0.y), P##3 = bhi(r0.y); \
    float P##4 = blo(r0.z), P##5 = bhi(r0.z), P##6 = blo(r0.w), P##7 = bhi(r0.w); \
    float P##8 = blo(r1.x), P##9 = bhi(r1.x), P##10 = blo(r1.y), P##11 = bhi(r1.y); \
    float P##12 = blo(r1.z), P##13 = bhi(r1.z), P##14 = blo(r1.w), P##15 = bhi(r1.w)

// pass 1: local scan from h=0; store final local h and decay product P.
// P_n = prod_t exp(dt_t*A_n) = exp(A_n * sum_t dt_t)  (exact) -> one dtsum.
__global__ __launch_bounds__(256) void scan_p1(
    const ushort* __restrict__ dtb, const ushort* __restrict__ xpb,
    const ushort* __restrict__ BC, const float* __restrict__ A_log,
    ushort* __restrict__ hloc, ushort* __restrict__ prod)
{
    int gid = blockIdx.x * 256 + threadIdx.x;   // 131072
    int d  = gid & (D_INNER - 1);
    int ch = (gid >> 11) & (NCH - 1);
    int b  = gid >> 15;
    LOAD_A16();
    float h0 = 0.f, h1 = 0.f, h2 = 0.f, h3 = 0.f, h4 = 0.f, h5 = 0.f, h6 = 0.f, h7 = 0.f;
    float h8 = 0.f, h9 = 0.f, h10 = 0.f, h11 = 0.f, h12 = 0.f, h13 = 0.f, h14 = 0.f, h15 = 0.f;
    float dtsum = 0.f;
    size_t mBase = (size_t)b * SEQ + (size_t)ch * TC;
    const ushort* dtp = dtb + mBase * D_INNER + d;
    const ushort* xpp = xpb + mBase * D_INNER + d;
    const uint4*  bcp = (const uint4*)(BC + mBase * 32);
    for (int t = 0; t < TC; ++t) {
        float dt = us2f(dtp[(size_t)t * D_INNER]);
        float xt = us2f(xpp[(size_t)t * D_INNER]);
        uint4 r0 = bcp[t * 4 + 0];
        uint4 r1 = bcp[t * 4 + 1];
        float dtx = dt * xt;
        dtsum += dt;
        UNPACK16(B, r0, r1);
        h0  = __expf(dt * A0)  * h0  + dtx * B0;
        h1  = __expf(dt * A1)  * h1  + dtx * B1;
        h2  = __expf(dt * A2)  * h2  + dtx * B2;
        h3  = __expf(dt * A3)  * h3  + dtx * B3;
        h4  = __expf(dt * A4)  * h4  + dtx * B4;
        h5  = __expf(dt * A5)  * h5  + dtx * B5;
        h6  = __expf(dt * A6)  * h6  + dtx * B6;
        h7  = __expf(dt * A7)  * h7  + dtx * B7;
        h8  = __expf(dt * A8)  * h8  + dtx * B8;
        h9  = __expf(dt * A9)  * h9  + dtx * B9;
        h10 = __expf(dt * A10) * h10 + dtx * B10;
        h11 = __expf(dt * A11) * h11 + dtx * B11;
        h12 = __expf(dt * A12) * h12 + dtx * B12;
        h13 = __expf(dt * A13) * h13 + dtx * B13;
        h14 = __expf(dt * A14) * h14 + dtx * B14;
        h15 = __expf(dt * A15) * h15 + dtx * B15;
    }
    size_t idx = ((size_t)(b * NCH + ch) * D_INNER + d) * D_STATE;
    uint4 ho, h2v, po, p2v;
    ho.x  = pk2(h0, h1);   ho.y  = pk2(h2, h3);
    ho.z  = pk2(h4, h5);   ho.w  = pk2(h6, h7);
    h2v.x = pk2(h8, h9);   h2v.y = pk2(h10, h11);
    h2v.z = pk2(h12, h13); h2v.w = pk2(h14, h15);
    po.x  = pk2(__expf(dtsum * A0),  __expf(dtsum * A1));
    po.y  = pk2(__expf(dtsum * A2),  __expf(dtsum * A3));
    po.z  = pk2(__expf(dtsum * A4),  __expf(dtsum * A5));
    po.w  = pk2(__expf(dtsum * A6),  __expf(dtsum * A7));
    p2v.x = pk2(__expf(dtsum * A8),  __expf(dtsum * A9));
    p2v.y = pk2(__expf(dtsum * A10), __expf(dtsum * A11));
    p2v.z = pk2(__expf(dtsum * A12), __expf(dtsum * A13));
    p2v.w = pk2(__expf(dtsum * A14), __expf(dtsum * A15));
    ((uint4*)(hloc + idx))[0] = ho; ((uint4*)(hloc + idx))[1] = h2v;
    ((uint4*)(prod + idx))[0] = po; ((uint4*)(prod + idx))[1] = p2v;
}

// pass 1.5: sequential combine over chunks; hloc becomes h_in per chunk
__global__ __launch_bounds__(256) void scan_mid(
    ushort* __restrict__ hloc, const ushort* __restrict__ prod)
{
    int gid = blockIdx.x * 256 + threadIdx.x;   // 131072 = b(2) d(11) n(4), n fastest
    int n = gid & 15, d = (gid >> 4) & (D_INNER - 1), b = gid >> 15;
    float h = 0.f;
#pragma unroll
    for (int ch = 0; ch < NCH; ++ch) {
        size_t idx = ((size_t)(b * NCH + ch) * D_INNER + d) * D_STATE + n;
        float old = us2f(hloc[idx]);
        float p   = us2f(prod[idx]);
        hloc[idx] = bf2us(h);
        h = old + p * h;
    }
}

// pass 2: rerun recurrence with correct h_in; yz = (C.h + D*x) * silu(z) in-place
__global__ __launch_bounds__(256) void scan_p2(
    const ushort* __restrict__ dtb, const ushort* __restrict__ xpb,
    const ushort* __restrict__ BC, const float* __restrict__ A_log,
    const float* __restrict__ D_param, const ushort* __restrict__ hin,
    ushort* __restrict__ zio)
{
    int gid = blockIdx.x * 256 + threadIdx.x;
    int d  = gid & (D_INNER - 1);
    int ch = (gid >> 11) & (NCH - 1);
    int b  = gid >> 15;
    LOAD_A16();
    float Dp = D_param[d];
    size_t idx = ((size_t)(b * NCH + ch) * D_INNER + d) * D_STATE;
    uint4 hr0 = ((const uint4*)(hin + idx))[0];
    uint4 hr1 = ((const uint4*)(hin + idx))[1];
    float h0 = blo(hr0.x), h1 = bhi(hr0.x), h2 = blo(hr0.y), h3 = bhi(hr0.y);
    float h4 = blo(hr0.z), h5 = bhi(hr0.z), h6 = blo(hr0.w), h7 = bhi(hr0.w);
    float h8 = blo(hr1.x), h9 = bhi(hr1.x), h10 = blo(hr1.y), h11 = bhi(hr1.y);
    float h12 = blo(hr1.z), h13 = bhi(hr1.z), h14 = blo(hr1.w), h15 = bhi(hr1.w);
    size_t mBase = (size_t)b * SEQ + (size_t)ch * TC;
    const ushort* dtp = dtb + mBase * D_INNER + d;
    const ushort* xpp = xpb + mBase * D_INNER + d;
    const uint4*  bcp = (const uint4*)(BC + mBase * 32);
    ushort* zp = zio + mBase * D_INNER + d;
    for (int t = 0; t < TC; ++t) {
        float dt = us2f(dtp[(size_t)t * D_INNER]);
        float xt = us2f(xpp[(size_t)t * D_INNER]);
        uint4 r0 = bcp[t * 4 + 0];
        uint4 r1 = bcp[t * 4 + 1];
        uint4 r2 = bcp[t * 4 + 2];
        uint4 r3 = bcp[t * 4 + 3];
        UNPACK16(B, r0, r1);
        UNPACK16(C, r2, r3);
        float dtx = dt * xt;
        float y = Dp * xt;
        h0  = __expf(dt * A0)  * h0  + dtx * B0;   y += h0  * C0;
        h1  = __expf(dt * A1)  * h1  + dtx * B1;   y += h1  * C1;
        h2  = __expf(dt * A2)  * h2  + dtx * B2;   y += h2  * C2;
        h3  = __expf(dt * A3)  * h3  + dtx * B3;   y += h3  * C3;
        h4  = __expf(dt * A4)  * h4  + dtx * B4;   y += h4  * C4;
        h5  = __expf(dt * A5)  * h5  + dtx * B5;   y += h5  * C5;
        h6  = __expf(dt * A6)  * h6  + dtx * B6;   y += h6  * C6;
        h7  = __expf(dt * A7)  * h7  + dtx * B7;   y += h7  * C7;
        h8  = __expf(dt * A8)  * h8  + dtx * B8;   y += h8  * C8;
        h9  = __expf(dt * A9)  * h9  + dtx * B9;   y += h9  * C9;
        h10 = __expf(dt * A10) * h10 + dtx * B10;  y += h10 * C10;
        h11 = __expf(dt * A11) * h11 + dtx * B11;  y += h11 * C11;
        h12 = __expf(dt * A12) * h12 + dtx * B12;  y += h12 * C12;
        h13 = __expf(dt * A13) * h13 + dtx * B13;  y += h13 * C13;
        h14 = __expf(dt * A14) * h14 + dtx * B14;  y += h14 * C14;
        h15 = __expf(dt * A15) * h15 + dtx * B15;  y += h15 * C15;
        float z = us2f(zp[(size_t)t * D_INNER]);
        zp[(size_t)t * D_INNER] = bf2us(y * z);
    }
}

// ------------------------------------------------------------------ launch
extern "C" void kernel_launch(void* const* d_in, const int* in_sizes, int n_in,
                              void* d_out, int out_size, void* d_ws, size_t ws_size,
                              hipStream_t stream)
{
    const float* x       = (const float*)d_in[0];
    const float* norm_w  = (const float*)d_in[1];
    const float* norm_b  = (const float*)d_in[2];
    const float* W_in    = (const float*)d_in[3];
    const float* conv_w  = (const float*)d_in[4];
    const float* conv_b  = (const float*)d_in[5];
    const float* A_log   = (const float*)d_in[6];
    const float* W_b     = (const float*)d_in[7];
    const float* W_c     = (const float*)d_in[8];
    const float* W_delta = (const float*)d_in[9];
    const float* b_delta = (const float*)d_in[10];
    const float* D_param = (const float*)d_in[11];
    const float* W_out   = (const float*)d_in[12];
    float* out = (float*)d_out;

    // ---- workspace: EXACTLY the proven 110,100,480-byte footprint (R2 lesson:
    //      210 MB overflowed d_ws and corrupted pristine inputs).
    char* ws = (char*)d_ws;
    char* R1 = ws;                          // 33,554,432
    char* R2 = R1 + (size_t)33554432;       // 33,554,432
    char* R3 = R2 + (size_t)33554432;       // 33,554,432
    char* R4 = R3 + (size_t)33554432;       //  8,912,896
    char* R5 = R4 + (size_t)8912896;        //    524,288  => 110,100,480

    // lifetimes:
    __hip_bfloat16* xnb  = (__hip_bfloat16*)R1;                 // ln .. gemm1
    __hip_bfloat16* wT1  = (__hip_bfloat16*)(R1 + 16777216);    // trW_in .. gemm1
    __hip_bfloat16* xp   = (__hip_bfloat16*)R1;                 // conv .. scan_p2
    __hip_bfloat16* xraw = (__hip_bfloat16*)R2;                 // gemm1 .. conv
    __hip_bfloat16* dtb  = (__hip_bfloat16*)R2;                 // gemm2 (softplus'd dt) .. scan_p2
    __hip_bfloat16* wT3  = (__hip_bfloat16*)R2;                 // trW_out .. gemm3 (over dead dtb)
    __hip_bfloat16* zio  = (__hip_bfloat16*)R3;                 // silu(z) then yz in-place
    __hip_bfloat16* wT2  = (__hip_bfloat16*)R4;                 // tr .. gemm2 (2176x2048)
    ushort*         hloc = (ushort*)R4;                         // scan_p1.. (4.19 MB, over dead wT2)
    ushort*         prodb= (ushort*)(R4 + 4194304);             // scan_p1.. (4.19 MB)
    __hip_bfloat16* BCb  = (__hip_bfloat16*)R5;                 // gemm2 .. scan (B|C rows)

    // 1. LayerNorm -> bf16
    ln_kernel<<<NTOK, 256, 0, stream>>>(x, norm_w, norm_b, xnb);

    // 2. W_in^T -> wT1
    transpose_cast<<<dim3(128, 32), dim3(32, 8), 0, stream>>>(W_in, wT1, 1024, 4096, 1024, 0);

    // 3. xz = xn @ W_in -> xraw (x-path) + silu(z) -> zio
    gemm_bt<1><<<dim3(NTOK / 128, 4096 / 128), 256, 0, stream>>>(
        xnb, wT1, NTOK, 4096, 1024, nullptr, xraw, zio, nullptr);

    // 4. [W_delta | W_b | W_c | 0]^T -> wT2
    transpose_cast<<<dim3(64, 64), dim3(32, 8), 0, stream>>>(W_delta, wT2, 2048, 2048, 2048, 0);
    transpose_cast<<<dim3(1, 64),  dim3(32, 8), 0, stream>>>(W_b,     wT2, 2048, 16,   2048, 2048);
    transpose_cast<<<dim3(1, 64),  dim3(32, 8), 0, stream>>>(W_c,     wT2, 2048, 16,   2048, 2064);
    zero_fill<<<96, 256, 0, stream>>>((uint4*)(wT2 + (size_t)2080 * 2048), 24576);

    // 5. conv + silu: xraw -> xp
    conv_silu<<<1024, 256, 0, stream>>>(xraw, conv_w, conv_b, xp);

    // 6. gemm2: dt = softplus(xp@W_delta + b_delta) -> dtb ; B|C -> BCb
    gemm_bt<2><<<dim3(NTOK / 128, NBIG / 128), 256, 0, stream>>>(
        xp, wT2, NTOK, NBIG, 2048, nullptr, dtb, BCb, b_delta);

    // 7. chunked scan, 16 states per thread (all named scalars, no arrays)
    scan_p1<<<512, 256, 0, stream>>>((const ushort*)dtb, (const ushort*)xp,
                                     (const ushort*)BCb, A_log, hloc, prodb);
    scan_mid<<<512, 256, 0, stream>>>(hloc, prodb);
    scan_p2<<<512, 256, 0, stream>>>((const ushort*)dtb, (const ushort*)xp,
                                     (const ushort*)BCb, A_log, D_param, hloc,
                                     (ushort*)zio);

    // 8. W_out^T -> wT3 (dtb region dead after scan_p2)
    transpose_cast<<<dim3(32, 64), dim3(32, 8), 0, stream>>>(W_out, wT3, 2048, 1024, 2048, 0);

    // 9. out = yz @ W_out + residual
    gemm_bt<3><<<dim3(NTOK / 128, D_MODEL / 128), 256, 0, stream>>>(
        zio, wT3, NTOK, D_MODEL, 2048, out, nullptr, nullptr, x);

    (void)in_sizes; (void)n_in; (void)out_size; (void)ws_size;
}

// Round 8
// 574.539 us; speedup vs baseline: 1.8444x; 1.0138x over previous
//
#include <hip/hip_runtime.h>
#include <hip/hip_bf16.h>

#define D_MODEL 1024
#define D_STATE 16
#define D_INNER 2048
#define BSZ     4
#define SEQ     2048
#define NTOK    (BSZ*SEQ)     /* 8192 tokens */
#define NBIG    2176          /* 2048 (delta) + 16 (B) + 16 (C) + pad to 17*128 */
#define NCH     16            /* scan chunks per sequence */
#define TC      128           /* scan chunk length */

typedef __attribute__((ext_vector_type(8))) short short8;
typedef __attribute__((ext_vector_type(4))) float floatx4;

__device__ __forceinline__ ushort bf2us(float f)
{
    union { __hip_bfloat16 h; ushort u; } c;
    c.h = __float2bfloat16(f);
    return c.u;
}
__device__ __forceinline__ float us2f(ushort u)
{
    union { uint u; float f; } c;
    c.u = ((uint)u) << 16;
    return c.f;
}
__device__ __forceinline__ uint pk2(float a, float b)
{
    return (uint)bf2us(a) | ((uint)bf2us(b) << 16);
}
__device__ __forceinline__ float blo(uint u) { return __uint_as_float(u << 16); }
__device__ __forceinline__ float bhi(uint u) { return __uint_as_float(u & 0xffff0000u); }
__device__ __forceinline__ float softplus_f(float v)
{
    return (v > 20.f) ? v : __logf(1.f + __expf(v));
}

// async global->LDS, 16B per lane; LDS dest = wave-uniform base + lane*16
__device__ __forceinline__ void load_lds16(const __hip_bfloat16* g, __hip_bfloat16* l)
{
    __builtin_amdgcn_global_load_lds(
        (const __attribute__((address_space(1))) char*)g,
        (__attribute__((address_space(3))) char*)l, 16, 0, 0);
}

// ---------------------------------------------------------------- LayerNorm
__global__ __launch_bounds__(256) void ln_kernel(
    const float* __restrict__ x, const float* __restrict__ w,
    const float* __restrict__ bvec, __hip_bfloat16* __restrict__ out)
{
    int token = blockIdx.x;
    int tid = threadIdx.x;
    const float4 v = ((const float4*)(x + (size_t)token * D_MODEL))[tid];
    float s  = v.x + v.y + v.z + v.w;
    float sq = v.x*v.x + v.y*v.y + v.z*v.z + v.w*v.w;
#pragma unroll
    for (int o = 32; o; o >>= 1) { s += __shfl_down(s, o, 64); sq += __shfl_down(sq, o, 64); }
    __shared__ float red[8];
    int wid = tid >> 6;
    if ((tid & 63) == 0) { red[wid] = s; red[wid + 4] = sq; }
    __syncthreads();
    s  = red[0] + red[1] + red[2] + red[3];
    sq = red[4] + red[5] + red[6] + red[7];
    float mu  = s * (1.f / D_MODEL);
    float var = sq * (1.f / D_MODEL) - mu * mu;
    float rs  = rsqrtf(var + 1e-5f);
    float4 wv = ((const float4*)w)[tid];
    float4 bv = ((const float4*)bvec)[tid];
    union { ushort4 u; __hip_bfloat16 h[4]; } p;
    p.h[0] = __float2bfloat16((v.x - mu) * rs * wv.x + bv.x);
    p.h[1] = __float2bfloat16((v.y - mu) * rs * wv.y + bv.y);
    p.h[2] = __float2bfloat16((v.z - mu) * rs * wv.z + bv.z);
    p.h[3] = __float2bfloat16((v.w - mu) * rs * wv.w + bv.w);
    ((ushort4*)(out + (size_t)token * D_MODEL))[tid] = p.u;
}

// ------------------------------------------------- transpose + cast fp32->bf16
__device__ __forceinline__ void tr_body(
    const float* __restrict__ src, __hip_bfloat16* __restrict__ dst,
    int R, int C, int dstStride, int dstRowOff, int bx, int by, int tx, int ty)
{
    __shared__ float tile[32][33];
#pragma unroll
    for (int i = 0; i < 4; ++i) {
        int r = by * 32 + ty + i * 8;
        int c = bx * 32 + tx;
        if (r < R && c < C) tile[ty + i * 8][tx] = src[(size_t)r * C + c];
    }
    __syncthreads();
#pragma unroll
    for (int i = 0; i < 4; ++i) {
        int c = bx * 32 + ty + i * 8;
        int r = by * 32 + tx;
        if (c < C && r < R)
            dst[(size_t)(dstRowOff + c) * dstStride + r] = __float2bfloat16(tile[tx][ty + i * 8]);
    }
}

__global__ __launch_bounds__(256) void transpose_cast(
    const float* __restrict__ src, __hip_bfloat16* __restrict__ dst,
    int R, int C, int dstStride, int dstRowOff)
{
    tr_body(src, dst, R, C, dstStride, dstRowOff,
            blockIdx.x, blockIdx.y, threadIdx.x, threadIdx.y);
}

// one merged weight-prep kernel: wT1 | wT2 main | W_b | W_c | zero-pad
// grid = 4096 + 4096 + 64 + 64 + 96 = 8416 blocks of (32,8)
__global__ __launch_bounds__(256) void prep_w(
    const float* __restrict__ W_in, const float* __restrict__ W_delta,
    const float* __restrict__ W_b, const float* __restrict__ W_c,
    __hip_bfloat16* __restrict__ wT1, __hip_bfloat16* __restrict__ wT2)
{
    int s = blockIdx.x;
    int tx = threadIdx.x, ty = threadIdx.y;
    if (s < 4096) {
        tr_body(W_in, wT1, 1024, 4096, 1024, 0, s & 127, s >> 7, tx, ty);
    } else if (s < 8192) {
        int q = s - 4096;
        tr_body(W_delta, wT2, 2048, 2048, 2048, 0, q & 63, q >> 6, tx, ty);
    } else if (s < 8256) {
        tr_body(W_b, wT2, 2048, 16, 2048, 2048, 0, s - 8192, tx, ty);
    } else if (s < 8320) {
        tr_body(W_c, wT2, 2048, 16, 2048, 2064, 0, s - 8256, tx, ty);
    } else {
        int i = (s - 8320) * 256 + ty * 32 + tx;   // < 24576
        uint4 z = {0, 0, 0, 0};
        ((uint4*)(wT2 + (size_t)2080 * 2048))[i] = z;
    }
}

// ---------------------------------------------------------------- bf16 GEMM
// C[M,N] = A[M,K] * BT[N,K]^T ; 128x128 tile, BK=64, 4 waves of 64x64.
// Staging: global_load_lds width=16, unpadded stride-64 LDS tiles with XOR
// swizzle phys_cg = cg ^ (row&7) (conflict-free; R6->R7: 8.9M conflicts -> 0).
template <int MODE>
__device__ __forceinline__ void gemm_body(
    const __hip_bfloat16* __restrict__ A, const __hip_bfloat16* __restrict__ BT,
    int M, int N, int K,
    float* __restrict__ outF,
    __hip_bfloat16* __restrict__ outB1, __hip_bfloat16* __restrict__ outB2,
    const float* __restrict__ extra)
{
    __shared__ __align__(16) __hip_bfloat16 As[128 * 64];
    __shared__ __align__(16) __hip_bfloat16 Bs[128 * 64];
    int tid = threadIdx.x;
    int m0 = blockIdx.x * 128;
    int n0 = blockIdx.y * 128;
    int wv = tid >> 6, lane = tid & 63;
    int wm = (wv >> 1) * 64, wn = (wv & 1) * 64;
    int lr = lane & 15, lq = lane >> 4;

    int srow = wv * 8 + (lane >> 3);
    int scg  = (lane & 7) ^ (lane >> 3);
    const __hip_bfloat16* Ag = A  + (size_t)(m0 + srow) * K + scg * 8;
    const __hip_bfloat16* Bg = BT + (size_t)(n0 + srow) * K + scg * 8;
    __hip_bfloat16* AsW = As + (wv * 8) * 64;
    __hip_bfloat16* BsW = Bs + (wv * 8) * 64;

    int swz = lq ^ (lr & 7);

    floatx4 acc[4][4] = {};

    for (int k0 = 0; k0 < K; k0 += 64) {
        __syncthreads();
#pragma unroll
        for (int i = 0; i < 4; ++i) {
            load_lds16(Ag + (size_t)(i * 32) * K + k0, AsW + i * 32 * 64);
            load_lds16(Bg + (size_t)(i * 32) * K + k0, BsW + i * 32 * 64);
        }
        __syncthreads();
#pragma unroll
        for (int kk = 0; kk < 2; ++kk) {
            int cofs = (swz ^ (kk << 2)) * 8;
            short8 af[4], bf[4];
#pragma unroll
            for (int mi = 0; mi < 4; ++mi)
                af[mi] = *(const short8*)(As + (wm + mi * 16 + lr) * 64 + cofs);
#pragma unroll
            for (int ni = 0; ni < 4; ++ni)
                bf[ni] = *(const short8*)(Bs + (wn + ni * 16 + lr) * 64 + cofs);
#pragma unroll
            for (int mi = 0; mi < 4; ++mi)
#pragma unroll
                for (int ni = 0; ni < 4; ++ni)
                    acc[mi][ni] = __builtin_amdgcn_mfma_f32_16x16x32_bf16(af[mi], bf[ni], acc[mi][ni], 0, 0, 0);
        }
    }

#pragma unroll
    for (int mi = 0; mi < 4; ++mi)
#pragma unroll
        for (int ni = 0; ni < 4; ++ni)
#pragma unroll
            for (int r = 0; r < 4; ++r) {
                int rg = m0 + wm + mi * 16 + lq * 4 + r;
                int cg = n0 + wn + ni * 16 + lr;
                float v = acc[mi][ni][r];
                if (MODE == 1) {
                    if (cg < D_INNER) {
                        outB1[(size_t)rg * D_INNER + cg] = __float2bfloat16(v);
                    } else {
                        float sv = v / (1.f + __expf(-v));
                        outB2[(size_t)rg * D_INNER + (cg - D_INNER)] = __float2bfloat16(sv);
                    }
                } else if (MODE == 2) {
                    if (cg < D_INNER) {
                        outB1[(size_t)rg * D_INNER + cg] = __float2bfloat16(softplus_f(v + extra[cg]));
                    } else if (cg < D_INNER + 32) {
                        outB2[(size_t)rg * 32 + (cg - D_INNER)] = __float2bfloat16(v);
                    }
                } else {
                    outF[(size_t)rg * D_MODEL + cg] = v + extra[(size_t)rg * D_MODEL + cg];
                }
            }
}

// distinct symbols so rocprof disambiguates the three GEMMs
__global__ __launch_bounds__(256) void gemm_xz(
    const __hip_bfloat16* __restrict__ A, const __hip_bfloat16* __restrict__ BT,
    int M, int N, int K, float* __restrict__ outF,
    __hip_bfloat16* __restrict__ o1, __hip_bfloat16* __restrict__ o2,
    const float* __restrict__ extra)
{ gemm_body<1>(A, BT, M, N, K, outF, o1, o2, extra); }

__global__ __launch_bounds__(256) void gemm_dbc(
    const __hip_bfloat16* __restrict__ A, const __hip_bfloat16* __restrict__ BT,
    int M, int N, int K, float* __restrict__ outF,
    __hip_bfloat16* __restrict__ o1, __hip_bfloat16* __restrict__ o2,
    const float* __restrict__ extra)
{ gemm_body<2>(A, BT, M, N, K, outF, o1, o2, extra); }

__global__ __launch_bounds__(256) void gemm_out(
    const __hip_bfloat16* __restrict__ A, const __hip_bfloat16* __restrict__ BT,
    int M, int N, int K, float* __restrict__ outF,
    __hip_bfloat16* __restrict__ o1, __hip_bfloat16* __restrict__ o2,
    const float* __restrict__ extra)
{ gemm_body<3>(A, BT, M, N, K, outF, o1, o2, extra); }

// ------------------------------------------- depthwise causal conv (K=4) + SiLU
__global__ __launch_bounds__(256) void conv_silu(
    const __hip_bfloat16* __restrict__ xin, const float* __restrict__ cw,
    const float* __restrict__ cb, __hip_bfloat16* __restrict__ xp)
{
    int gid = blockIdx.x * 256 + threadIdx.x;
    int d = gid & (D_INNER - 1);
    int rest = gid >> 11;
    int b = rest & 3;
    int ch = rest >> 2;          // 0..31
    int t0 = ch * 64;
    float w0 = cw[d * 4 + 0], w1 = cw[d * 4 + 1], w2 = cw[d * 4 + 2], w3 = cw[d * 4 + 3];
    float bias = cb[d];
    const __hip_bfloat16* base = xin + (size_t)b * SEQ * D_INNER + d;
    __hip_bfloat16* ob = xp + (size_t)b * SEQ * D_INNER + d;
    float xm3 = (t0 >= 3) ? __bfloat162float(base[(size_t)(t0 - 3) * D_INNER]) : 0.f;
    float xm2 = (t0 >= 2) ? __bfloat162float(base[(size_t)(t0 - 2) * D_INNER]) : 0.f;
    float xm1 = (t0 >= 1) ? __bfloat162float(base[(size_t)(t0 - 1) * D_INNER]) : 0.f;
#pragma unroll 4
    for (int t = t0; t < t0 + 64; ++t) {
        float xcur = __bfloat162float(base[(size_t)t * D_INNER]);
        float v = bias + w0 * xm3 + w1 * xm2 + w2 * xm1 + w3 * xcur;
        float sv = v / (1.f + __expf(-v));
        ob[(size_t)t * D_INNER] = __float2bfloat16(sv);
        xm3 = xm2; xm2 = xm1; xm1 = xcur;
    }
}

// ------------------------------------------------------------ chunked scan
// One thread owns ALL 16 states of one (b, d, chunk). NO local arrays
// (R5 lesson: arrays -> scratch spill). Software prefetch of t+1 loads.
// gid: d = low 11 bits (coalesced dt/xt/z), ch next 4, b top 2.

#define LOAD_A16() \
    const float4* Ar = (const float4*)(A_log + (size_t)d * D_STATE); \
    float4 aA = Ar[0], aB = Ar[1], aC = Ar[2], aD = Ar[3]; \
    float A0 = -__expf(aA.x), A1 = -__expf(aA.y), A2 = -__expf(aA.z), A3 = -__expf(aA.w); \
    float A4 = -__expf(aB.x), A5 = -__expf(aB.y), A6 = -__expf(aB.z), A7 = -__expf(aB.w); \
    float A8 = -__expf(aC.x), A9 = -__expf(aC.y), A10 = -__expf(aC.z), A11 = -__expf(aC.w); \
    float A12 = -__expf(aD.x), A13 = -__expf(aD.y), A14 = -__expf(aD.z), A15 = -__expf(aD.w)

#define UNPACK16(P, r0, r1) \
    float P##0 = blo(r0.x), P##1 = bhi(r0.x), P##2 = blo(r0.y), P##3 = bhi(r0.y); \
    float P##4 = blo(r0.z), P##5 = bhi(r0.z), P##6 = blo(r0.w), P##7 = bhi(r0.w); \
    float P##8 = blo(r1.x), P##9 = bhi(r1.x), P##10 = blo(r1.y), P##11 = bhi(r1.y); \
    float P##12 = blo(r1.z), P##13 = bhi(r1.z), P##14 = blo(r1.w), P##15 = bhi(r1.w)

#define SCAN_STEP_B() do { \
    float dtx = dt * xt; \
    h0  = __expf(dt * A0)  * h0  + dtx * B0; \
    h1  = __expf(dt * A1)  * h1  + dtx * B1; \
    h2  = __expf(dt * A2)  * h2  + dtx * B2; \
    h3  = __expf(dt * A3)  * h3  + dtx * B3; \
    h4  = __expf(dt * A4)  * h4  + dtx * B4; \
    h5  = __expf(dt * A5)  * h5  + dtx * B5; \
    h6  = __expf(dt * A6)  * h6  + dtx * B6; \
    h7  = __expf(dt * A7)  * h7  + dtx * B7; \
    h8  = __expf(dt * A8)  * h8  + dtx * B8; \
    h9  = __expf(dt * A9)  * h9  + dtx * B9; \
    h10 = __expf(dt * A10) * h10 + dtx * B10; \
    h11 = __expf(dt * A11) * h11 + dtx * B11; \
    h12 = __expf(dt * A12) * h12 + dtx * B12; \
    h13 = __expf(dt * A13) * h13 + dtx * B13; \
    h14 = __expf(dt * A14) * h14 + dtx * B14; \
    h15 = __expf(dt * A15) * h15 + dtx * B15; \
} while (0)

// pass 1: local scan from h=0; store final local h and decay product P.
// P_n = exp(A_n * sum_t dt_t) (exact product identity) -> one dtsum.
__global__ __launch_bounds__(256) void scan_p1(
    const ushort* __restrict__ dtb, const ushort* __restrict__ xpb,
    const ushort* __restrict__ BC, const float* __restrict__ A_log,
    ushort* __restrict__ hloc, ushort* __restrict__ prod)
{
    int gid = blockIdx.x * 256 + threadIdx.x;   // 131072
    int d  = gid & (D_INNER - 1);
    int ch = (gid >> 11) & (NCH - 1);
    int b  = gid >> 15;
    LOAD_A16();
    float h0 = 0.f, h1 = 0.f, h2 = 0.f, h3 = 0.f, h4 = 0.f, h5 = 0.f, h6 = 0.f, h7 = 0.f;
    float h8 = 0.f, h9 = 0.f, h10 = 0.f, h11 = 0.f, h12 = 0.f, h13 = 0.f, h14 = 0.f, h15 = 0.f;
    float dtsum = 0.f;
    size_t mBase = (size_t)b * SEQ + (size_t)ch * TC;
    const ushort* dtp = dtb + mBase * D_INNER + d;
    const ushort* xpp = xpb + mBase * D_INNER + d;
    const uint4*  bcp = (const uint4*)(BC + mBase * 32);
    float dt = us2f(dtp[0]);
    float xt = us2f(xpp[0]);
    uint4 r0 = bcp[0], r1 = bcp[1];
    for (int t = 0; t < TC - 1; ++t) {
        // prefetch t+1
        float dt_n = us2f(dtp[(size_t)(t + 1) * D_INNER]);
        float xt_n = us2f(xpp[(size_t)(t + 1) * D_INNER]);
        uint4 r0_n = bcp[(t + 1) * 4 + 0];
        uint4 r1_n = bcp[(t + 1) * 4 + 1];
        {
            UNPACK16(B, r0, r1);
            dtsum += dt;
            SCAN_STEP_B();
        }
        dt = dt_n; xt = xt_n; r0 = r0_n; r1 = r1_n;
    }
    {
        UNPACK16(B, r0, r1);
        dtsum += dt;
        SCAN_STEP_B();
    }
    size_t idx = ((size_t)(b * NCH + ch) * D_INNER + d) * D_STATE;
    uint4 ho, h2v, po, p2v;
    ho.x  = pk2(h0, h1);   ho.y  = pk2(h2, h3);
    ho.z  = pk2(h4, h5);   ho.w  = pk2(h6, h7);
    h2v.x = pk2(h8, h9);   h2v.y = pk2(h10, h11);
    h2v.z = pk2(h12, h13); h2v.w = pk2(h14, h15);
    po.x  = pk2(__expf(dtsum * A0),  __expf(dtsum * A1));
    po.y  = pk2(__expf(dtsum * A2),  __expf(dtsum * A3));
    po.z  = pk2(__expf(dtsum * A4),  __expf(dtsum * A5));
    po.w  = pk2(__expf(dtsum * A6),  __expf(dtsum * A7));
    p2v.x = pk2(__expf(dtsum * A8),  __expf(dtsum * A9));
    p2v.y = pk2(__expf(dtsum * A10), __expf(dtsum * A11));
    p2v.z = pk2(__expf(dtsum * A12), __expf(dtsum * A13));
    p2v.w = pk2(__expf(dtsum * A14), __expf(dtsum * A15));
    ((uint4*)(hloc + idx))[0] = ho; ((uint4*)(hloc + idx))[1] = h2v;
    ((uint4*)(prod + idx))[0] = po; ((uint4*)(prod + idx))[1] = p2v;
}

// pass 2: per-thread combine of h_in over prior chunks (replaces scan_mid
// launch; identical math: h = hloc[j] + P[j]*h for j<ch, kept in fp32),
// then rerun recurrence; yz = (C.h + D*x) * silu(z) in-place.
__global__ __launch_bounds__(256) void scan_p2(
    const ushort* __restrict__ dtb, const ushort* __restrict__ xpb,
    const ushort* __restrict__ BC, const float* __restrict__ A_log,
    const float* __restrict__ D_param, const ushort* __restrict__ hloc,
    const ushort* __restrict__ prod, ushort* __restrict__ zio)
{
    int gid = blockIdx.x * 256 + threadIdx.x;
    int d  = gid & (D_INNER - 1);
    int ch = (gid >> 11) & (NCH - 1);
    int b  = gid >> 15;
    LOAD_A16();
    float Dp = D_param[d];
    float h0 = 0.f, h1 = 0.f, h2 = 0.f, h3 = 0.f, h4 = 0.f, h5 = 0.f, h6 = 0.f, h7 = 0.f;
    float h8 = 0.f, h9 = 0.f, h10 = 0.f, h11 = 0.f, h12 = 0.f, h13 = 0.f, h14 = 0.f, h15 = 0.f;
    for (int j = 0; j < ch; ++j) {   // wave-uniform trip (d = low gid bits)
        size_t jdx = ((size_t)(b * NCH + j) * D_INNER + d) * D_STATE;
        uint4 a0 = ((const uint4*)(hloc + jdx))[0];
        uint4 a1 = ((const uint4*)(hloc + jdx))[1];
        uint4 q0 = ((const uint4*)(prod + jdx))[0];
        uint4 q1 = ((const uint4*)(prod + jdx))[1];
        h0  = blo(a0.x) + blo(q0.x) * h0;   h1  = bhi(a0.x) + bhi(q0.x) * h1;
        h2  = blo(a0.y) + blo(q0.y) * h2;   h3  = bhi(a0.y) + bhi(q0.y) * h3;
        h4  = blo(a0.z) + blo(q0.z) * h4;   h5  = bhi(a0.z) + bhi(q0.z) * h5;
        h6  = blo(a0.w) + blo(q0.w) * h6;   h7  = bhi(a0.w) + bhi(q0.w) * h7;
        h8  = blo(a1.x) + blo(q1.x) * h8;   h9  = bhi(a1.x) + bhi(q1.x) * h9;
        h10 = blo(a1.y) + blo(q1.y) * h10;  h11 = bhi(a1.y) + bhi(q1.y) * h11;
        h12 = blo(a1.z) + blo(q1.z) * h12;  h13 = bhi(a1.z) + bhi(q1.z) * h13;
        h14 = blo(a1.w) + blo(q1.w) * h14;  h15 = bhi(a1.w) + bhi(q1.w) * h15;
    }
    size_t mBase = (size_t)b * SEQ + (size_t)ch * TC;
    const ushort* dtp = dtb + mBase * D_INNER + d;
    const ushort* xpp = xpb + mBase * D_INNER + d;
    const uint4*  bcp = (const uint4*)(BC + mBase * 32);
    ushort* zp = zio + mBase * D_INNER + d;
    float dt = us2f(dtp[0]);
    float xt = us2f(xpp[0]);
    uint4 r0 = bcp[0], r1 = bcp[1], r2 = bcp[2], r3 = bcp[3];
    for (int t = 0; t < TC; ++t) {
        float dt_n = 0.f, xt_n = 0.f;
        uint4 r0_n = {0,0,0,0}, r1_n = {0,0,0,0}, r2_n = {0,0,0,0}, r3_n = {0,0,0,0};
        if (t < TC - 1) {
            dt_n = us2f(dtp[(size_t)(t + 1) * D_INNER]);
            xt_n = us2f(xpp[(size_t)(t + 1) * D_INNER]);
            r0_n = bcp[(t + 1) * 4 + 0];
            r1_n = bcp[(t + 1) * 4 + 1];
            r2_n = bcp[(t + 1) * 4 + 2];
            r3_n = bcp[(t + 1) * 4 + 3];
        }
        {
            UNPACK16(B, r0, r1);
            UNPACK16(C, r2, r3);
            float dtx = dt * xt;
            float y = Dp * xt;
            h0  = __expf(dt * A0)  * h0  + dtx * B0;   y += h0  * C0;
            h1  = __expf(dt * A1)  * h1  + dtx * B1;   y += h1  * C1;
            h2  = __expf(dt * A2)  * h2  + dtx * B2;   y += h2  * C2;
            h3  = __expf(dt * A3)  * h3  + dtx * B3;   y += h3  * C3;
            h4  = __expf(dt * A4)  * h4  + dtx * B4;   y += h4  * C4;
            h5  = __expf(dt * A5)  * h5  + dtx * B5;   y += h5  * C5;
            h6  = __expf(dt * A6)  * h6  + dtx * B6;   y += h6  * C6;
            h7  = __expf(dt * A7)  * h7  + dtx * B7;   y += h7  * C7;
            h8  = __expf(dt * A8)  * h8  + dtx * B8;   y += h8  * C8;
            h9  = __expf(dt * A9)  * h9  + dtx * B9;   y += h9  * C9;
            h10 = __expf(dt * A10) * h10 + dtx * B10;  y += h10 * C10;
            h11 = __expf(dt * A11) * h11 + dtx * B11;  y += h11 * C11;
            h12 = __expf(dt * A12) * h12 + dtx * B12;  y += h12 * C12;
            h13 = __expf(dt * A13) * h13 + dtx * B13;  y += h13 * C13;
            h14 = __expf(dt * A14) * h14 + dtx * B14;  y += h14 * C14;
            h15 = __expf(dt * A15) * h15 + dtx * B15;  y += h15 * C15;
            float z = us2f(zp[(size_t)t * D_INNER]);
            zp[(size_t)t * D_INNER] = bf2us(y * z);
        }
        dt = dt_n; xt = xt_n; r0 = r0_n; r1 = r1_n; r2 = r2_n; r3 = r3_n;
    }
}

// ------------------------------------------------------------------ launch
extern "C" void kernel_launch(void* const* d_in, const int* in_sizes, int n_in,
                              void* d_out, int out_size, void* d_ws, size_t ws_size,
                              hipStream_t stream)
{
    const float* x       = (const float*)d_in[0];
    const float* norm_w  = (const float*)d_in[1];
    const float* norm_b  = (const float*)d_in[2];
    const float* W_in    = (const float*)d_in[3];
    const float* conv_w  = (const float*)d_in[4];
    const float* conv_b  = (const float*)d_in[5];
    const float* A_log   = (const float*)d_in[6];
    const float* W_b     = (const float*)d_in[7];
    const float* W_c     = (const float*)d_in[8];
    const float* W_delta = (const float*)d_in[9];
    const float* b_delta = (const float*)d_in[10];
    const float* D_param = (const float*)d_in[11];
    const float* W_out   = (const float*)d_in[12];
    float* out = (float*)d_out;

    // ---- workspace: EXACTLY the proven 110,100,480-byte footprint (R2 lesson:
    //      210 MB overflowed d_ws and corrupted pristine inputs).
    char* ws = (char*)d_ws;
    char* R1 = ws;                          // 33,554,432
    char* R2 = R1 + (size_t)33554432;       // 33,554,432
    char* R3 = R2 + (size_t)33554432;       // 33,554,432
    char* R4 = R3 + (size_t)33554432;       //  8,912,896
    char* R5 = R4 + (size_t)8912896;        //    524,288  => 110,100,480

    // lifetimes:
    __hip_bfloat16* xnb  = (__hip_bfloat16*)R1;                 // ln .. gemm1
    __hip_bfloat16* wT1  = (__hip_bfloat16*)(R1 + 16777216);    // prep .. gemm1
    __hip_bfloat16* xp   = (__hip_bfloat16*)R1;                 // conv .. scan_p2
    __hip_bfloat16* xraw = (__hip_bfloat16*)R2;                 // gemm1 .. conv
    __hip_bfloat16* dtb  = (__hip_bfloat16*)R2;                 // gemm2 (softplus'd dt) .. scan_p2
    __hip_bfloat16* wT3  = (__hip_bfloat16*)R2;                 // trW_out .. gemm3 (over dead dtb)
    __hip_bfloat16* zio  = (__hip_bfloat16*)R3;                 // silu(z) then yz in-place
    __hip_bfloat16* wT2  = (__hip_bfloat16*)R4;                 // prep .. gemm2 (2176x2048)
    ushort*         hloc = (ushort*)R4;                         // scan_p1.. (4.19 MB, over dead wT2)
    ushort*         prodb= (ushort*)(R4 + 4194304);             // scan_p1.. (4.19 MB)
    __hip_bfloat16* BCb  = (__hip_bfloat16*)R5;                 // gemm2 .. scan (B|C rows)

    // 1. LayerNorm -> bf16
    ln_kernel<<<NTOK, 256, 0, stream>>>(x, norm_w, norm_b, xnb);

    // 2. all weight prep in ONE kernel (wT1 + wT2 + B + C + zero-pad)
    prep_w<<<8416, dim3(32, 8), 0, stream>>>(W_in, W_delta, W_b, W_c, wT1, wT2);

    // 3. xz = xn @ W_in -> xraw (x-path) + silu(z) -> zio
    gemm_xz<<<dim3(NTOK / 128, 4096 / 128), 256, 0, stream>>>(
        xnb, wT1, NTOK, 4096, 1024, nullptr, xraw, zio, nullptr);

    // 4. conv + silu: xraw -> xp
    conv_silu<<<1024, 256, 0, stream>>>(xraw, conv_w, conv_b, xp);

    // 5. gemm2: dt = softplus(xp@W_delta + b_delta) -> dtb ; B|C -> BCb
    gemm_dbc<<<dim3(NTOK / 128, NBIG / 128), 256, 0, stream>>>(
        xp, wT2, NTOK, NBIG, 2048, nullptr, dtb, BCb, b_delta);

    // 6. chunked scan (scan_mid folded into p2's per-thread combine)
    scan_p1<<<512, 256, 0, stream>>>((const ushort*)dtb, (const ushort*)xp,
                                     (const ushort*)BCb, A_log, hloc, prodb);
    scan_p2<<<512, 256, 0, stream>>>((const ushort*)dtb, (const ushort*)xp,
                                     (const ushort*)BCb, A_log, D_param,
                                     hloc, prodb, (ushort*)zio);

    // 7. W_out^T -> wT3 (dtb region dead after scan_p2)
    transpose_cast<<<dim3(32, 64), dim3(32, 8), 0, stream>>>(W_out, wT3, 2048, 1024, 2048, 0);

    // 8. out = yz @ W_out + residual
    gemm_out<<<dim3(NTOK / 128, D_MODEL / 128), 256, 0, stream>>>(
        zio, wT3, NTOK, D_MODEL, 2048, out, nullptr, nullptr, x);

    (void)in_sizes; (void)n_in; (void)out_size; (void)ws_size;
}